// Round 7
// baseline (261.927 us; speedup 1.0000x reference)
//
#include <hip/hip_runtime.h>
#include <math.h>

constexpr int BB = 2;
constexpr int SS = 2048;
constexpr int DM = 1024;
constexpr int NH = 16;
constexpr int KD = 64;
constexpr int OUT_ELEMS  = BB*SS*DM;     // 4194304 fp32 (output 0 region)
constexpr int PRES_HALF  = BB*NH*SS*KD;  // 4194304 fp32 (k or v)
#define NEGSENT (-1e30f)

typedef __attribute__((ext_vector_type(8))) short short8;   // 8 x bf16 bits
typedef __attribute__((ext_vector_type(4))) short short4v;  // 4 x bf16 bits
typedef __attribute__((ext_vector_type(4))) float f32x4;

__device__ __forceinline__ float us2f(unsigned short u) {
  union { unsigned int ui; float f; } c; c.ui = ((unsigned int)u) << 16; return c.f;
}
__device__ __forceinline__ short f2s(float f) {
  // round-to-nearest-even bf16 (finite inputs only)
  union { float f; unsigned int u; } c; c.f = f;
  return (short)((c.u + 0x7FFFu + ((c.u >> 16) & 1u)) >> 16);
}

#define GLOAD_LDS16(g, l) \
  __builtin_amdgcn_global_load_lds((const __attribute__((address_space(1))) void*)(g), \
                                   (__attribute__((address_space(3))) void*)(l), 16, 0, 0)

// ---------------- prep: cast x[4096,1024] fp32 -> bf16 ----------------------
__global__ __launch_bounds__(256)
void cast_x_k(const float* __restrict__ x, short* __restrict__ xb) {
  const size_t i = ((size_t)blockIdx.x * 256 + threadIdx.x) * 4;
  const float4 v = *(const float4*)(x + i);
  short4v s; s.x = f2s(v.x); s.y = f2s(v.y); s.z = f2s(v.z); s.w = f2s(v.w);
  *(short4v*)(xb + i) = s;
}

// ---------------- prep: transpose w[1024,N] fp32 -> wT[N,1024] bf16 ---------
__global__ __launch_bounds__(256)
void transpose_k(const float* __restrict__ w, int N, short* __restrict__ wt) {
  __shared__ float tl[32][33];
  const int tx = threadIdx.x & 31, ty = threadIdx.x >> 5;   // 32 x 8
  const int n0 = blockIdx.x * 32, k0 = blockIdx.y * 32;
  #pragma unroll
  for (int i = 0; i < 4; ++i) {
    const int kk = ty + i * 8;
    tl[kk][tx] = w[(size_t)(k0 + kk) * N + n0 + tx];
  }
  __syncthreads();
  #pragma unroll
  for (int i = 0; i < 4; ++i) {
    const int nn = ty + i * 8;
    wt[(size_t)(n0 + nn) * 1024 + k0 + tx] = f2s(tl[tx][nn]);
  }
}

// ---------------- MFMA GEMM core (m97 structure, BK=64) ---------------------
// BK 32->64: halves barrier pairs per K-loop (32->16). LDS 2x16KB = 32 KB;
// occupancy stays VGPR-capped (~3 blocks/CU) so the bigger tile is free.
__device__ __forceinline__ void mfma_tile_loop(
    const short* __restrict__ A, const short* __restrict__ Bt,
    int m0, int n0, short* Asm, short* Bsm, f32x4 (*acc)[4]) {
  const int tid = threadIdx.x;
  const int lane = tid & 63;
  const int w = tid >> 6;
  const int wm = (w >> 1) * 64, wn = (w & 1) * 64;
  const int ln15 = lane & 15, quad = lane >> 4;
  for (int k0 = 0; k0 < 1024; k0 += 64) {
    #pragma unroll
    for (int j = 0; j < 4; ++j) {
      const int e = j * 256 + tid;          // 0..1023
      const int r = e >> 3, cq = e & 7;     // row 0..127, 16B-chunk 0..7
      GLOAD_LDS16(A  + (size_t)(m0 + r) * 1024 + k0 + cq * 8, Asm + e * 8);
      GLOAD_LDS16(Bt + (size_t)(n0 + r) * 1024 + k0 + cq * 8, Bsm + e * 8);
    }
    __syncthreads();                        // drains vmcnt before barrier
    #pragma unroll
    for (int kk = 0; kk < 2; ++kk) {
      short8 af[4], bf[4];
      #pragma unroll
      for (int t = 0; t < 4; ++t)
        af[t] = *(const short8*)(Asm + (wm + t * 16 + ln15) * 64 + kk * 32 + quad * 8);
      #pragma unroll
      for (int t = 0; t < 4; ++t)
        bf[t] = *(const short8*)(Bsm + (wn + t * 16 + ln15) * 64 + kk * 32 + quad * 8);
      #pragma unroll
      for (int tm = 0; tm < 4; ++tm)
        #pragma unroll
        for (int tn = 0; tn < 4; ++tn)
          acc[tm][tn] = __builtin_amdgcn_mfma_f32_16x16x32_bf16(
              af[tm], bf[tn], acc[tm][tn], 0, 0, 0);
    }
    __syncthreads();
  }
}

// ---------------- QKV GEMM: routes v,q,k = split(qkv) ----------------------
//   n in [0,1024)    -> v fp32 -> outf[8M..12M) = present[1]; + bf16 V^T
//   n in [1024,2048) -> q bf16 -> qbf [B,H,S,KD]
//   n in [2048,3072) -> k fp32 -> outf[4M..8M)  = present[0]; + bf16 K
__global__ __launch_bounds__(256)
void qkv_mfma_k(const short* __restrict__ A, const short* __restrict__ Bt,
                const float* __restrict__ bias, short* __restrict__ qbf,
                float* __restrict__ outf, short* __restrict__ kbf,
                short* __restrict__ vbft) {
  __shared__ short Asm[128 * 64];
  __shared__ short Bsm[128 * 64];
  const int n0 = blockIdx.x * 128, m0 = blockIdx.y * 128;
  f32x4 acc[4][4] = {};
  mfma_tile_loop(A, Bt, m0, n0, Asm, Bsm, acc);
  const int lane = threadIdx.x & 63;
  const int w = threadIdx.x >> 6;
  const int wm = (w >> 1) * 64, wn = (w & 1) * 64;
  const int col = lane & 15, row4 = (lane >> 4) * 4;
  #pragma unroll
  for (int tm = 0; tm < 4; ++tm) {
    #pragma unroll
    for (int tn = 0; tn < 4; ++tn) {
      const int n = n0 + wn + tn * 16 + col;
      #pragma unroll
      for (int r = 0; r < 4; ++r) {
        const int m = m0 + wm + tm * 16 + row4 + r;
        const float val = acc[tm][tn][r] + bias[n];
        const int bb = m >> 11, s = m & 2047;
        const int c = n & 1023, h = c >> 6, d = c & 63;
        const size_t idx = ((size_t)(bb * NH + h) * SS + s) * KD + d;
        if (n < DM) {
          outf[(size_t)OUT_ELEMS + (size_t)PRES_HALF + idx] = val;   // v fp32
          if (kbf) vbft[((size_t)(bb * NH + h) * KD + d) * SS + s] = f2s(val);
        } else if (n < 2 * DM) {
          qbf[idx] = f2s(val);                                        // q bf16
        } else {
          outf[(size_t)OUT_ELEMS + idx] = val;                        // k fp32
          if (kbf) kbf[idx] = f2s(val);
        }
      }
    }
  }
}

// ---------------- Output projection: o @ w_projT + b -> out0 fp32 -----------
__global__ __launch_bounds__(256)
void proj_mfma_k(const short* __restrict__ A, const short* __restrict__ Bt,
                 const float* __restrict__ bias, float* __restrict__ outf) {
  __shared__ short Asm[128 * 64];
  __shared__ short Bsm[128 * 64];
  const int n0 = blockIdx.x * 128, m0 = blockIdx.y * 128;
  f32x4 acc[4][4] = {};
  mfma_tile_loop(A, Bt, m0, n0, Asm, Bsm, acc);
  const int lane = threadIdx.x & 63;
  const int w = threadIdx.x >> 6;
  const int wm = (w >> 1) * 64, wn = (w & 1) * 64;
  const int col = lane & 15, row4 = (lane >> 4) * 4;
  #pragma unroll
  for (int tm = 0; tm < 4; ++tm) {
    #pragma unroll
    for (int tn = 0; tn < 4; ++tn) {
      const int n = n0 + wn + tn * 16 + col;
      const float b = bias[n];
      #pragma unroll
      for (int r = 0; r < 4; ++r) {
        const int m = m0 + wm + tm * 16 + row4 + r;
        outf[(size_t)m * DM + n] = acc[tm][tn][r] + b;
      }
    }
  }
}

// ---------------- staging: one 64-key chunk of K + V^T, 256 threads ---------
__device__ __forceinline__ void stage_kv4(const short* __restrict__ Kg,
                                          const short* __restrict__ Vg,
                                          int kb, short* Ksb, short* Vtb,
                                          int tid) {
  #pragma unroll
  for (int rd = 0; rd < 2; ++rd) {
    const int i = rd * 256 + tid;        // 0..511 : row = i>>3, grp = i&7
    const int row = i >> 3, grp = i & 7;
    const int sw = (grp ^ (row & 7)) << 3;
    GLOAD_LDS16(Kg + (size_t)(kb + row) * KD + sw, Ksb + i * 8);
    GLOAD_LDS16(Vg + (size_t)row * SS + kb + sw, Vtb + i * 8);
  }
}

// ---------------- MFMA causal flash attention (R6 structure + VALU diet) ----
// 4 waves/block, K/V double-buffered, balanced XCD-bijective grid (R6).
// New: T13 defer-max (skip rescale when __all(pmax - m <= 8), wave-uniform),
// fma-folded P-compute (exp2(fma(S,SC2,-m*SC2))), max3-friendly reduce tree.
__global__ __launch_bounds__(256)
void attn_mfma6_k(const short* __restrict__ qbf, const short* __restrict__ kbf,
                  const short* __restrict__ vbft, short* __restrict__ obf) {
  __shared__ short Ks[2][64 * 64];    // K chunk  [key][d], swizzled
  __shared__ short Vt[2][64 * 64];    // V^T chunk [d][key], swizzled
  __shared__ short Ps[4][16 * 64];    // per-wave P [qrow][key], swizzled
  const int bid = blockIdx.x;
  const int xcd = bid & 7, g = bid >> 3;
  const int rr  = g & 31, rnd = g >> 5;           // round = head index 0..3
  const int bh  = (xcd << 2) | rnd;               // 4 heads per XCD
  const int qb  = (rnd & 1) ? rr : 31 - rr;       // alternate-round flip
  const int q0  = qb * 64;
  const int tid = threadIdx.x;
  const int w   = tid >> 6;
  const int lane = tid & 63;
  const int ln15 = lane & 15, quad = lane >> 4;
  const int rswz = (ln15 & 7) << 3;               // fragment-read swizzle
  const float SC2 = 0.125f * 1.44269504f;         // scale * log2(e)
  const float THR = 8.0f;                         // defer-max threshold (raw)

  // Q fragments for this wave's 16 rows: row = ln15, k = kt*32 + quad*8
  short8 aq[2];
  {
    const short* qp = qbf + ((size_t)bh * SS + q0 + w * 16) * KD;
    aq[0] = *(const short8*)(qp + (size_t)ln15 * KD + quad * 8);
    aq[1] = *(const short8*)(qp + (size_t)ln15 * KD + 32 + quad * 8);
  }
  f32x4 O[4] = {};                    // [tn], rows quad*4+r
  float mreg[4], lreg[4];             // [r]
  #pragma unroll
  for (int r = 0; r < 4; ++r) { mreg[r] = NEGSENT; lreg[r] = 0.f; }

  const short* Kg = kbf  + (size_t)bh * SS * KD;
  const short* Vg = vbft + (size_t)bh * KD * SS;
  short* Pw = Ps[w];
  const int nch = qb + 1;

  stage_kv4(Kg, Vg, 0, Ks[0], Vt[0], tid);   // prologue: chunk 0 -> buf 0
  __syncthreads();

  for (int ch = 0; ch < nch; ++ch) {
    const int cur = ch & 1;
    if (ch + 1 < nch)                        // issue next-chunk loads first
      stage_kv4(Kg, Vg, (ch + 1) * 64, Ks[cur ^ 1], Vt[cur ^ 1], tid);
    const short* Kc = Ks[cur];
    const short* Vc = Vt[cur];

    // ---- QK^T: S[16 q][64 k] ----
    f32x4 S[4] = {};
    #pragma unroll
    for (int kt = 0; kt < 2; ++kt) {
      short8 bk[4];
      #pragma unroll
      for (int tn = 0; tn < 4; ++tn)
        bk[tn] = *(const short8*)(Kc + (tn * 16 + ln15) * 64 + ((kt * 32 + quad * 8) ^ rswz));
      #pragma unroll
      for (int tn = 0; tn < 4; ++tn)
        S[tn] = __builtin_amdgcn_mfma_f32_16x16x32_bf16(aq[kt], bk[tn], S[tn], 0, 0, 0);
    }

    // ---- causal mask on the diagonal chunk ----
    if (ch == qb) {
      const int rowl = w * 16 + quad * 4;
      #pragma unroll
      for (int tn = 0; tn < 4; ++tn) {
        const int colk = tn * 16 + ln15;
        #pragma unroll
        for (int r = 0; r < 4; ++r)
          if (colk > rowl + r) S[tn][r] = NEGSENT;
      }
    }

    // ---- row max (v_max3-friendly tree + 4-step shfl reduce) ----
    float pmax[4];
    #pragma unroll
    for (int r = 0; r < 4; ++r) {
      float mx = fmaxf(fmaxf(fmaxf(S[0][r], S[1][r]), S[2][r]), S[3][r]);
      mx = fmaxf(mx, __shfl_xor(mx, 1, 64));
      mx = fmaxf(mx, __shfl_xor(mx, 2, 64));
      mx = fmaxf(mx, __shfl_xor(mx, 4, 64));
      mx = fmaxf(mx, __shfl_xor(mx, 8, 64));
      pmax[r] = mx;
    }

    // ---- T13 defer-max: rescale only when some row grew past THR ----
    bool okl = true;
    #pragma unroll
    for (int r = 0; r < 4; ++r) okl = okl && (pmax[r] - mreg[r] <= THR);
    if (!__all((int)okl)) {                 // wave-uniform branch
      #pragma unroll
      for (int r = 0; r < 4; ++r) {
        const float mn = fmaxf(mreg[r], pmax[r]);
        const float al = exp2f((mreg[r] - mn) * SC2);
        mreg[r] = mn;
        lreg[r] *= al;
        O[0][r] *= al; O[1][r] *= al; O[2][r] *= al; O[3][r] *= al;
      }
    }

    // ---- P = exp2(fma(S,SC2,-m*SC2)); accumulate l; write P (swizzled) ----
    #pragma unroll
    for (int r = 0; r < 4; ++r) {
      const float mnsc = mreg[r] * SC2;
      const int prow = quad * 4 + r;
      const int rs = (prow & 7) << 3;
      float p0 = exp2f(fmaf(S[0][r], SC2, -mnsc));
      float p1 = exp2f(fmaf(S[1][r], SC2, -mnsc));
      float p2 = exp2f(fmaf(S[2][r], SC2, -mnsc));
      float p3 = exp2f(fmaf(S[3][r], SC2, -mnsc));
      lreg[r] += (p0 + p1) + (p2 + p3);
      Pw[prow * 64 + ((0 * 16 + ln15) ^ rs)] = f2s(p0);
      Pw[prow * 64 + ((1 * 16 + ln15) ^ rs)] = f2s(p1);
      Pw[prow * 64 + ((2 * 16 + ln15) ^ rs)] = f2s(p2);
      Pw[prow * 64 + ((3 * 16 + ln15) ^ rs)] = f2s(p3);
    }
    asm volatile("s_waitcnt lgkmcnt(0)" ::: "memory");  // own P writes landed
    __builtin_amdgcn_sched_barrier(0);                  // rule 18

    // ---- PV: O += P @ V ----
    #pragma unroll
    for (int kt = 0; kt < 2; ++kt) {
      short8 ap = *(const short8*)(Pw + ln15 * 64 + ((kt * 32 + quad * 8) ^ rswz));
      short8 bv[4];
      #pragma unroll
      for (int tn = 0; tn < 4; ++tn)
        bv[tn] = *(const short8*)(Vc + (tn * 16 + ln15) * 64 + ((kt * 32 + quad * 8) ^ rswz));
      #pragma unroll
      for (int tn = 0; tn < 4; ++tn)
        O[tn] = __builtin_amdgcn_mfma_f32_16x16x32_bf16(ap, bv[tn], O[tn], 0, 0, 0);
    }
    __syncthreads();   // next buf staged+visible; prev reads done
  }

  // ---- finalize l and write o token-major ----
  #pragma unroll
  for (int r = 0; r < 4; ++r) {
    float l = lreg[r];
    l += __shfl_xor(l, 1, 64);
    l += __shfl_xor(l, 2, 64);
    l += __shfl_xor(l, 4, 64);
    l += __shfl_xor(l, 8, 64);
    lreg[r] = 1.f / fmaxf(l, 1e-30f);
  }
  const int bb = bh >> 4, h = bh & 15;
  short* ob = obf + ((size_t)bb * SS + q0 + w * 16) * DM + h * KD;
  #pragma unroll
  for (int tn = 0; tn < 4; ++tn)
    #pragma unroll
    for (int r = 0; r < 4; ++r)
      ob[(size_t)(quad * 4 + r) * DM + tn * 16 + ln15] = f2s(O[tn][r] * lreg[r]);
}

// ---------------- legacy fp32 flash attention (fallback, small ws) ----------
__global__ __launch_bounds__(256)
void attn_k(const short* __restrict__ qbf, const float* __restrict__ pres,
            short* __restrict__ obf) {
  __shared__ float Ksf[32][64];
  __shared__ float Vsf[32][64];
  const int bh = blockIdx.x;
  const int q0 = ((int)gridDim.y - 1 - (int)blockIdx.y) * 64;
  const int t  = threadIdx.x;
  const int part = t & 3;
  const int row  = t >> 2;
  const int qr   = q0 + row;
  const int dbase = part * 16;
  const size_t qoff = ((size_t)bh * SS + qr) * KD + dbase;
  float q[16], o[16];
  #pragma unroll
  for (int i = 0; i < 16; ++i) q[i] = us2f((unsigned short)qbf[qoff + i]);
  #pragma unroll
  for (int i = 0; i < 16; ++i) o[i] = 0.f;
  float m = NEGSENT, l = 0.f;
  const float* Kb = pres + (size_t)bh * SS * KD;
  const float* Vb = pres + (size_t)PRES_HALF + (size_t)bh * SS * KD;
  const int nch = (q0 + 64) / 32;
  for (int ch = 0; ch < nch; ++ch) {
    const int kbase = ch * 32;
    __syncthreads();
    {
      const float4* ksrc = (const float4*)(Kb + (size_t)kbase * KD);
      const float4* vsrc = (const float4*)(Vb + (size_t)kbase * KD);
      float4* kdst = (float4*)&Ksf[0][0];
      float4* vdst = (float4*)&Vsf[0][0];
      #pragma unroll
      for (int i = 0; i < 2; ++i) {
        kdst[t + i * 256] = ksrc[t + i * 256];
        vdst[t + i * 256] = vsrc[t + i * 256];
      }
    }
    __syncthreads();
    float sc[32];
    #pragma unroll
    for (int kk = 0; kk < 32; ++kk) {
      float s = 0.f;
      #pragma unroll
      for (int i = 0; i < 16; ++i) s = fmaf(q[i], Ksf[kk][dbase + i], s);
      s += __shfl_xor(s, 1, 64);
      s += __shfl_xor(s, 2, 64);
      sc[kk] = (kbase + kk <= qr) ? s * 0.125f : NEGSENT;
    }
    float mc = sc[0];
    #pragma unroll
    for (int kk = 1; kk < 32; ++kk) mc = fmaxf(mc, sc[kk]);
    const float mn = fmaxf(m, mc);
    const float alpha = __expf(m - mn);
    l *= alpha;
    #pragma unroll
    for (int i = 0; i < 16; ++i) o[i] *= alpha;
    #pragma unroll
    for (int kk = 0; kk < 32; ++kk) {
      const float p = __expf(sc[kk] - mn);
      l += p;
      #pragma unroll
      for (int i = 0; i < 16; ++i) o[i] = fmaf(p, Vsf[kk][dbase + i], o[i]);
    }
    m = mn;
  }
  const float inv = 1.f / fmaxf(l, 1e-30f);
  const int bb = bh >> 4, h = bh & 15;
  const size_t ooff = ((size_t)(bb * SS + qr)) * DM + h * KD + dbase;
  #pragma unroll
  for (int i = 0; i < 16; ++i) obf[ooff + i] = f2s(o[i] * inv);
}

extern "C" void kernel_launch(void* const* d_in, const int* in_sizes, int n_in,
                              void* d_out, int out_size, void* d_ws, size_t ws_size,
                              hipStream_t stream) {
  const float* x      = (const float*)d_in[0];
  const float* w_attn = (const float*)d_in[2];
  const float* b_attn = (const float*)d_in[3];
  const float* w_proj = (const float*)d_in[4];
  const float* b_proj = (const float*)d_in[5];
  float* outf = (float*)d_out;   // fp32: [out0 4M | k 4M | v 4M] elements

  constexpr size_t MB = 1024 * 1024;
  if (ws_size >= 24 * MB) {
    // ---- MFMA-attention path ----
    // ws (shorts): [0,4M) x_bf then o_bf (lifetimes disjoint) |
    //              [4M,7M) w_attn_T | [7M,8M) w_proj_T | [8M,12M) q_bf
    // d_out out0 region (dead until proj): [0,4M) k_bf | [4M,8M) v_bfT
    short* ws0   = (short*)d_ws;
    short* x_bf  = ws0;
    short* o_bf  = ws0;
    short* wat_t = ws0 + (size_t)4 * 1024 * 1024;
    short* wpt_t = ws0 + (size_t)7 * 1024 * 1024;
    short* q_bf  = ws0 + (size_t)8 * 1024 * 1024;
    short* k_bf  = (short*)d_out;
    short* v_bft = k_bf + (size_t)PRES_HALF;

    cast_x_k<<<4096, 256, 0, stream>>>(x, x_bf);
    transpose_k<<<dim3(96, 32), 256, 0, stream>>>(w_attn, 3 * DM, wat_t);
    transpose_k<<<dim3(32, 32), 256, 0, stream>>>(w_proj, DM, wpt_t);

    qkv_mfma_k<<<dim3(24, 32), 256, 0, stream>>>(x_bf, wat_t, b_attn, q_bf, outf,
                                                 k_bf, v_bft);

    attn_mfma6_k<<<dim3(BB * NH * (SS / 64)), 256, 0, stream>>>(q_bf, k_bf, v_bft, o_bf);

    proj_mfma_k<<<dim3(8, 32), 256, 0, stream>>>(o_bf, wpt_t, b_proj, outf);
  } else {
    // ---- legacy fp32-attention fallback ----
    short* x_bf;
    short* q_bf;
    short* wat_t;
    short* wpt_t;
    short* o_bf;
    if (ws_size >= 16 * MB) {
      short* ws = (short*)d_ws;
      x_bf  = (short*)d_out;                 // out0 [0,8MB) dead until proj
      q_bf  = x_bf + OUT_ELEMS;              // out0 [8MB,16MB)
      wat_t = ws;
      wpt_t = wat_t + 3 * DM * DM;
      o_bf  = wat_t + 4 * DM * DM;
    } else {
      x_bf  = (short*)d_out;
      q_bf  = x_bf + OUT_ELEMS;
      wat_t = (short*)d_in[1];
      wpt_t = wat_t + 3 * DM * DM;
      o_bf  = wat_t + 4 * DM * DM;
    }
    cast_x_k<<<4096, 256, 0, stream>>>(x, x_bf);
    transpose_k<<<dim3(96, 32), 256, 0, stream>>>(w_attn, 3 * DM, wat_t);
    transpose_k<<<dim3(32, 32), 256, 0, stream>>>(w_proj, DM, wpt_t);
    qkv_mfma_k<<<dim3(24, 32), 256, 0, stream>>>(x_bf, wat_t, b_attn, q_bf, outf,
                                                 nullptr, nullptr);
    attn_k<<<dim3(BB * NH, SS / 64), 256, 0, stream>>>(q_bf, outf + OUT_ELEMS, o_bf);
    proj_mfma_k<<<dim3(8, 32), 256, 0, stream>>>(o_bf, wpt_t, b_proj, outf);
  }
}

// Round 8
// 251.571 us; speedup vs baseline: 1.0412x; 1.0412x over previous
//
#include <hip/hip_runtime.h>
#include <math.h>

constexpr int BB = 2;
constexpr int SS = 2048;
constexpr int DM = 1024;
constexpr int NH = 16;
constexpr int KD = 64;
constexpr int OUT_ELEMS  = BB*SS*DM;     // 4194304 fp32 (output 0 region)
constexpr int PRES_HALF  = BB*NH*SS*KD;  // 4194304 fp32 (k or v)
#define NEGSENT (-1e30f)

typedef __attribute__((ext_vector_type(8))) short short8;   // 8 x bf16 bits
typedef __attribute__((ext_vector_type(4))) short short4v;  // 4 x bf16 bits
typedef __attribute__((ext_vector_type(4))) float f32x4;

__device__ __forceinline__ float us2f(unsigned short u) {
  union { unsigned int ui; float f; } c; c.ui = ((unsigned int)u) << 16; return c.f;
}
__device__ __forceinline__ short f2s(float f) {
  // round-to-nearest-even bf16 (finite inputs only)
  union { float f; unsigned int u; } c; c.f = f;
  return (short)((c.u + 0x7FFFu + ((c.u >> 16) & 1u)) >> 16);
}

#define GLOAD_LDS16(g, l) \
  __builtin_amdgcn_global_load_lds((const __attribute__((address_space(1))) void*)(g), \
                                   (__attribute__((address_space(3))) void*)(l), 16, 0, 0)

// ---------------- prep: cast x[4096,1024] fp32 -> bf16 ----------------------
__global__ __launch_bounds__(256)
void cast_x_k(const float* __restrict__ x, short* __restrict__ xb) {
  const size_t i = ((size_t)blockIdx.x * 256 + threadIdx.x) * 4;
  const float4 v = *(const float4*)(x + i);
  short4v s; s.x = f2s(v.x); s.y = f2s(v.y); s.z = f2s(v.z); s.w = f2s(v.w);
  *(short4v*)(xb + i) = s;
}

// ---------------- prep: transpose w[1024,N] fp32 -> wT[N,1024] bf16 ---------
__global__ __launch_bounds__(256)
void transpose_k(const float* __restrict__ w, int N, short* __restrict__ wt) {
  __shared__ float tl[32][33];
  const int tx = threadIdx.x & 31, ty = threadIdx.x >> 5;   // 32 x 8
  const int n0 = blockIdx.x * 32, k0 = blockIdx.y * 32;
  #pragma unroll
  for (int i = 0; i < 4; ++i) {
    const int kk = ty + i * 8;
    tl[kk][tx] = w[(size_t)(k0 + kk) * N + n0 + tx];
  }
  __syncthreads();
  #pragma unroll
  for (int i = 0; i < 4; ++i) {
    const int nn = ty + i * 8;
    wt[(size_t)(n0 + nn) * 1024 + k0 + tx] = f2s(tl[tx][nn]);
  }
}

// ---------------- MFMA GEMM core (BK=64, XOR-swizzled LDS) ------------------
// BK=64 halves barrier pairs vs BK=32 (16 vs 32). The 128B row stride would
// be a 16-way bank conflict (R7: 9.4M conflicts); fixed with the attn-proven
// pattern: pre-swizzled GLOBAL source chunk (cq ^= row&7), linear LDS dest
// (rule 21), and fragment reads XORed with (ln15&7)<<3 — 0 conflicts.
__device__ __forceinline__ void mfma_tile_loop(
    const short* __restrict__ A, const short* __restrict__ Bt,
    int m0, int n0, short* Asm, short* Bsm, f32x4 (*acc)[4]) {
  const int tid = threadIdx.x;
  const int lane = tid & 63;
  const int w = tid >> 6;
  const int wm = (w >> 1) * 64, wn = (w & 1) * 64;
  const int ln15 = lane & 15, quad = lane >> 4;
  const int rswz = (ln15 & 7) << 3;         // fragment-read swizzle (shorts)
  for (int k0 = 0; k0 < 1024; k0 += 64) {
    #pragma unroll
    for (int j = 0; j < 4; ++j) {
      const int e = j * 256 + tid;          // 0..1023
      const int r = e >> 3, cq = e & 7;     // row 0..127, 16B-chunk 0..7
      const int sw = (cq ^ (r & 7)) << 3;   // swizzled source offset (shorts)
      GLOAD_LDS16(A  + (size_t)(m0 + r) * 1024 + k0 + sw, Asm + e * 8);
      GLOAD_LDS16(Bt + (size_t)(n0 + r) * 1024 + k0 + sw, Bsm + e * 8);
    }
    __syncthreads();                        // drains vmcnt before barrier
    #pragma unroll
    for (int kk = 0; kk < 2; ++kk) {
      short8 af[4], bf[4];
      #pragma unroll
      for (int t = 0; t < 4; ++t)
        af[t] = *(const short8*)(Asm + (wm + t * 16 + ln15) * 64 + ((kk * 32 + quad * 8) ^ rswz));
      #pragma unroll
      for (int t = 0; t < 4; ++t)
        bf[t] = *(const short8*)(Bsm + (wn + t * 16 + ln15) * 64 + ((kk * 32 + quad * 8) ^ rswz));
      #pragma unroll
      for (int tm = 0; tm < 4; ++tm)
        #pragma unroll
        for (int tn = 0; tn < 4; ++tn)
          acc[tm][tn] = __builtin_amdgcn_mfma_f32_16x16x32_bf16(
              af[tm], bf[tn], acc[tm][tn], 0, 0, 0);
    }
    __syncthreads();
  }
}

// ---------------- QKV GEMM: routes v,q,k = split(qkv) ----------------------
//   n in [0,1024)    -> v fp32 -> outf[8M..12M) = present[1]; + bf16 V^T
//   n in [1024,2048) -> q bf16 -> qbf [B,H,S,KD]
//   n in [2048,3072) -> k fp32 -> outf[4M..8M)  = present[0]; + bf16 K
__global__ __launch_bounds__(256)
void qkv_mfma_k(const short* __restrict__ A, const short* __restrict__ Bt,
                const float* __restrict__ bias, short* __restrict__ qbf,
                float* __restrict__ outf, short* __restrict__ kbf,
                short* __restrict__ vbft) {
  __shared__ short Asm[128 * 64];
  __shared__ short Bsm[128 * 64];
  const int n0 = blockIdx.x * 128, m0 = blockIdx.y * 128;
  f32x4 acc[4][4] = {};
  mfma_tile_loop(A, Bt, m0, n0, Asm, Bsm, acc);
  const int lane = threadIdx.x & 63;
  const int w = threadIdx.x >> 6;
  const int wm = (w >> 1) * 64, wn = (w & 1) * 64;
  const int col = lane & 15, row4 = (lane >> 4) * 4;
  #pragma unroll
  for (int tm = 0; tm < 4; ++tm) {
    #pragma unroll
    for (int tn = 0; tn < 4; ++tn) {
      const int n = n0 + wn + tn * 16 + col;
      #pragma unroll
      for (int r = 0; r < 4; ++r) {
        const int m = m0 + wm + tm * 16 + row4 + r;
        const float val = acc[tm][tn][r] + bias[n];
        const int bb = m >> 11, s = m & 2047;
        const int c = n & 1023, h = c >> 6, d = c & 63;
        const size_t idx = ((size_t)(bb * NH + h) * SS + s) * KD + d;
        if (n < DM) {
          outf[(size_t)OUT_ELEMS + (size_t)PRES_HALF + idx] = val;   // v fp32
          if (kbf) vbft[((size_t)(bb * NH + h) * KD + d) * SS + s] = f2s(val);
        } else if (n < 2 * DM) {
          qbf[idx] = f2s(val);                                        // q bf16
        } else {
          outf[(size_t)OUT_ELEMS + idx] = val;                        // k fp32
          if (kbf) kbf[idx] = f2s(val);
        }
      }
    }
  }
}

// ---------------- Output projection: o @ w_projT + b -> out0 fp32 -----------
__global__ __launch_bounds__(256)
void proj_mfma_k(const short* __restrict__ A, const short* __restrict__ Bt,
                 const float* __restrict__ bias, float* __restrict__ outf) {
  __shared__ short Asm[128 * 64];
  __shared__ short Bsm[128 * 64];
  const int n0 = blockIdx.x * 128, m0 = blockIdx.y * 128;
  f32x4 acc[4][4] = {};
  mfma_tile_loop(A, Bt, m0, n0, Asm, Bsm, acc);
  const int lane = threadIdx.x & 63;
  const int w = threadIdx.x >> 6;
  const int wm = (w >> 1) * 64, wn = (w & 1) * 64;
  const int col = lane & 15, row4 = (lane >> 4) * 4;
  #pragma unroll
  for (int tm = 0; tm < 4; ++tm) {
    #pragma unroll
    for (int tn = 0; tn < 4; ++tn) {
      const int n = n0 + wn + tn * 16 + col;
      const float b = bias[n];
      #pragma unroll
      for (int r = 0; r < 4; ++r) {
        const int m = m0 + wm + tm * 16 + row4 + r;
        outf[(size_t)m * DM + n] = acc[tm][tn][r] + b;
      }
    }
  }
}

// ---------------- staging: one 64-key chunk of K + V^T, 256 threads ---------
__device__ __forceinline__ void stage_kv4(const short* __restrict__ Kg,
                                          const short* __restrict__ Vg,
                                          int kb, short* Ksb, short* Vtb,
                                          int tid) {
  #pragma unroll
  for (int rd = 0; rd < 2; ++rd) {
    const int i = rd * 256 + tid;        // 0..511 : row = i>>3, grp = i&7
    const int row = i >> 3, grp = i & 7;
    const int sw = (grp ^ (row & 7)) << 3;
    GLOAD_LDS16(Kg + (size_t)(kb + row) * KD + sw, Ksb + i * 8);
    GLOAD_LDS16(Vg + (size_t)row * SS + kb + sw, Vtb + i * 8);
  }
}

// ---------------- MFMA causal flash attention (R6 structure + VALU diet) ----
// 4 waves/block, K/V double-buffered, balanced XCD-bijective grid.
// T13 defer-max (skip rescale when __all(pmax - m <= 8), wave-uniform),
// fma-folded P-compute (exp2(fma(S,SC2,-m*SC2))), max3-friendly reduce tree.
__global__ __launch_bounds__(256)
void attn_mfma6_k(const short* __restrict__ qbf, const short* __restrict__ kbf,
                  const short* __restrict__ vbft, short* __restrict__ obf) {
  __shared__ short Ks[2][64 * 64];    // K chunk  [key][d], swizzled
  __shared__ short Vt[2][64 * 64];    // V^T chunk [d][key], swizzled
  __shared__ short Ps[4][16 * 64];    // per-wave P [qrow][key], swizzled
  const int bid = blockIdx.x;
  const int xcd = bid & 7, g = bid >> 3;
  const int rr  = g & 31, rnd = g >> 5;           // round = head index 0..3
  const int bh  = (xcd << 2) | rnd;               // 4 heads per XCD
  const int qb  = (rnd & 1) ? rr : 31 - rr;       // alternate-round flip
  const int q0  = qb * 64;
  const int tid = threadIdx.x;
  const int w   = tid >> 6;
  const int lane = tid & 63;
  const int ln15 = lane & 15, quad = lane >> 4;
  const int rswz = (ln15 & 7) << 3;               // fragment-read swizzle
  const float SC2 = 0.125f * 1.44269504f;         // scale * log2(e)
  const float THR = 8.0f;                         // defer-max threshold (raw)

  // Q fragments for this wave's 16 rows: row = ln15, k = kt*32 + quad*8
  short8 aq[2];
  {
    const short* qp = qbf + ((size_t)bh * SS + q0 + w * 16) * KD;
    aq[0] = *(const short8*)(qp + (size_t)ln15 * KD + quad * 8);
    aq[1] = *(const short8*)(qp + (size_t)ln15 * KD + 32 + quad * 8);
  }
  f32x4 O[4] = {};                    // [tn], rows quad*4+r
  float mreg[4], lreg[4];             // [r]
  #pragma unroll
  for (int r = 0; r < 4; ++r) { mreg[r] = NEGSENT; lreg[r] = 0.f; }

  const short* Kg = kbf  + (size_t)bh * SS * KD;
  const short* Vg = vbft + (size_t)bh * KD * SS;
  short* Pw = Ps[w];
  const int nch = qb + 1;

  stage_kv4(Kg, Vg, 0, Ks[0], Vt[0], tid);   // prologue: chunk 0 -> buf 0
  __syncthreads();

  for (int ch = 0; ch < nch; ++ch) {
    const int cur = ch & 1;
    if (ch + 1 < nch)                        // issue next-chunk loads first
      stage_kv4(Kg, Vg, (ch + 1) * 64, Ks[cur ^ 1], Vt[cur ^ 1], tid);
    const short* Kc = Ks[cur];
    const short* Vc = Vt[cur];

    // ---- QK^T: S[16 q][64 k] ----
    f32x4 S[4] = {};
    #pragma unroll
    for (int kt = 0; kt < 2; ++kt) {
      short8 bk[4];
      #pragma unroll
      for (int tn = 0; tn < 4; ++tn)
        bk[tn] = *(const short8*)(Kc + (tn * 16 + ln15) * 64 + ((kt * 32 + quad * 8) ^ rswz));
      #pragma unroll
      for (int tn = 0; tn < 4; ++tn)
        S[tn] = __builtin_amdgcn_mfma_f32_16x16x32_bf16(aq[kt], bk[tn], S[tn], 0, 0, 0);
    }

    // ---- causal mask on the diagonal chunk ----
    if (ch == qb) {
      const int rowl = w * 16 + quad * 4;
      #pragma unroll
      for (int tn = 0; tn < 4; ++tn) {
        const int colk = tn * 16 + ln15;
        #pragma unroll
        for (int r = 0; r < 4; ++r)
          if (colk > rowl + r) S[tn][r] = NEGSENT;
      }
    }

    // ---- row max (v_max3-friendly tree + 4-step shfl reduce) ----
    float pmax[4];
    #pragma unroll
    for (int r = 0; r < 4; ++r) {
      float mx = fmaxf(fmaxf(fmaxf(S[0][r], S[1][r]), S[2][r]), S[3][r]);
      mx = fmaxf(mx, __shfl_xor(mx, 1, 64));
      mx = fmaxf(mx, __shfl_xor(mx, 2, 64));
      mx = fmaxf(mx, __shfl_xor(mx, 4, 64));
      mx = fmaxf(mx, __shfl_xor(mx, 8, 64));
      pmax[r] = mx;
    }

    // ---- T13 defer-max: rescale only when some row grew past THR ----
    bool okl = true;
    #pragma unroll
    for (int r = 0; r < 4; ++r) okl = okl && (pmax[r] - mreg[r] <= THR);
    if (!__all((int)okl)) {                 // wave-uniform branch
      #pragma unroll
      for (int r = 0; r < 4; ++r) {
        const float mn = fmaxf(mreg[r], pmax[r]);
        const float al = exp2f((mreg[r] - mn) * SC2);
        mreg[r] = mn;
        lreg[r] *= al;
        O[0][r] *= al; O[1][r] *= al; O[2][r] *= al; O[3][r] *= al;
      }
    }

    // ---- P = exp2(fma(S,SC2,-m*SC2)); accumulate l; write P (swizzled) ----
    #pragma unroll
    for (int r = 0; r < 4; ++r) {
      const float mnsc = mreg[r] * SC2;
      const int prow = quad * 4 + r;
      const int rs = (prow & 7) << 3;
      float p0 = exp2f(fmaf(S[0][r], SC2, -mnsc));
      float p1 = exp2f(fmaf(S[1][r], SC2, -mnsc));
      float p2 = exp2f(fmaf(S[2][r], SC2, -mnsc));
      float p3 = exp2f(fmaf(S[3][r], SC2, -mnsc));
      lreg[r] += (p0 + p1) + (p2 + p3);
      Pw[prow * 64 + ((0 * 16 + ln15) ^ rs)] = f2s(p0);
      Pw[prow * 64 + ((1 * 16 + ln15) ^ rs)] = f2s(p1);
      Pw[prow * 64 + ((2 * 16 + ln15) ^ rs)] = f2s(p2);
      Pw[prow * 64 + ((3 * 16 + ln15) ^ rs)] = f2s(p3);
    }
    asm volatile("s_waitcnt lgkmcnt(0)" ::: "memory");  // own P writes landed
    __builtin_amdgcn_sched_barrier(0);                  // rule 18

    // ---- PV: O += P @ V ----
    #pragma unroll
    for (int kt = 0; kt < 2; ++kt) {
      short8 ap = *(const short8*)(Pw + ln15 * 64 + ((kt * 32 + quad * 8) ^ rswz));
      short8 bv[4];
      #pragma unroll
      for (int tn = 0; tn < 4; ++tn)
        bv[tn] = *(const short8*)(Vc + (tn * 16 + ln15) * 64 + ((kt * 32 + quad * 8) ^ rswz));
      #pragma unroll
      for (int tn = 0; tn < 4; ++tn)
        O[tn] = __builtin_amdgcn_mfma_f32_16x16x32_bf16(ap, bv[tn], O[tn], 0, 0, 0);
    }
    __syncthreads();   // next buf staged+visible; prev reads done
  }

  // ---- finalize l and write o token-major ----
  #pragma unroll
  for (int r = 0; r < 4; ++r) {
    float l = lreg[r];
    l += __shfl_xor(l, 1, 64);
    l += __shfl_xor(l, 2, 64);
    l += __shfl_xor(l, 4, 64);
    l += __shfl_xor(l, 8, 64);
    lreg[r] = 1.f / fmaxf(l, 1e-30f);
  }
  const int bb = bh >> 4, h = bh & 15;
  short* ob = obf + ((size_t)bb * SS + q0 + w * 16) * DM + h * KD;
  #pragma unroll
  for (int tn = 0; tn < 4; ++tn)
    #pragma unroll
    for (int r = 0; r < 4; ++r)
      ob[(size_t)(quad * 4 + r) * DM + tn * 16 + ln15] = f2s(O[tn][r] * lreg[r]);
}

// ---------------- legacy fp32 flash attention (fallback, small ws) ----------
__global__ __launch_bounds__(256)
void attn_k(const short* __restrict__ qbf, const float* __restrict__ pres,
            short* __restrict__ obf) {
  __shared__ float Ksf[32][64];
  __shared__ float Vsf[32][64];
  const int bh = blockIdx.x;
  const int q0 = ((int)gridDim.y - 1 - (int)blockIdx.y) * 64;
  const int t  = threadIdx.x;
  const int part = t & 3;
  const int row  = t >> 2;
  const int qr   = q0 + row;
  const int dbase = part * 16;
  const size_t qoff = ((size_t)bh * SS + qr) * KD + dbase;
  float q[16], o[16];
  #pragma unroll
  for (int i = 0; i < 16; ++i) q[i] = us2f((unsigned short)qbf[qoff + i]);
  #pragma unroll
  for (int i = 0; i < 16; ++i) o[i] = 0.f;
  float m = NEGSENT, l = 0.f;
  const float* Kb = pres + (size_t)bh * SS * KD;
  const float* Vb = pres + (size_t)PRES_HALF + (size_t)bh * SS * KD;
  const int nch = (q0 + 64) / 32;
  for (int ch = 0; ch < nch; ++ch) {
    const int kbase = ch * 32;
    __syncthreads();
    {
      const float4* ksrc = (const float4*)(Kb + (size_t)kbase * KD);
      const float4* vsrc = (const float4*)(Vb + (size_t)kbase * KD);
      float4* kdst = (float4*)&Ksf[0][0];
      float4* vdst = (float4*)&Vsf[0][0];
      #pragma unroll
      for (int i = 0; i < 2; ++i) {
        kdst[t + i * 256] = ksrc[t + i * 256];
        vdst[t + i * 256] = vsrc[t + i * 256];
      }
    }
    __syncthreads();
    float sc[32];
    #pragma unroll
    for (int kk = 0; kk < 32; ++kk) {
      float s = 0.f;
      #pragma unroll
      for (int i = 0; i < 16; ++i) s = fmaf(q[i], Ksf[kk][dbase + i], s);
      s += __shfl_xor(s, 1, 64);
      s += __shfl_xor(s, 2, 64);
      sc[kk] = (kbase + kk <= qr) ? s * 0.125f : NEGSENT;
    }
    float mc = sc[0];
    #pragma unroll
    for (int kk = 1; kk < 32; ++kk) mc = fmaxf(mc, sc[kk]);
    const float mn = fmaxf(m, mc);
    const float alpha = __expf(m - mn);
    l *= alpha;
    #pragma unroll
    for (int i = 0; i < 16; ++i) o[i] *= alpha;
    #pragma unroll
    for (int kk = 0; kk < 32; ++kk) {
      const float p = __expf(sc[kk] - mn);
      l += p;
      #pragma unroll
      for (int i = 0; i < 16; ++i) o[i] = fmaf(p, Vsf[kk][dbase + i], o[i]);
    }
    m = mn;
  }
  const float inv = 1.f / fmaxf(l, 1e-30f);
  const int bb = bh >> 4, h = bh & 15;
  const size_t ooff = ((size_t)(bb * SS + qr)) * DM + h * KD + dbase;
  #pragma unroll
  for (int i = 0; i < 16; ++i) obf[ooff + i] = f2s(o[i] * inv);
}

extern "C" void kernel_launch(void* const* d_in, const int* in_sizes, int n_in,
                              void* d_out, int out_size, void* d_ws, size_t ws_size,
                              hipStream_t stream) {
  const float* x      = (const float*)d_in[0];
  const float* w_attn = (const float*)d_in[2];
  const float* b_attn = (const float*)d_in[3];
  const float* w_proj = (const float*)d_in[4];
  const float* b_proj = (const float*)d_in[5];
  float* outf = (float*)d_out;   // fp32: [out0 4M | k 4M | v 4M] elements

  constexpr size_t MB = 1024 * 1024;
  if (ws_size >= 24 * MB) {
    // ---- MFMA-attention path ----
    // ws (shorts): [0,4M) x_bf then o_bf (lifetimes disjoint) |
    //              [4M,7M) w_attn_T | [7M,8M) w_proj_T | [8M,12M) q_bf
    // d_out out0 region (dead until proj): [0,4M) k_bf | [4M,8M) v_bfT
    short* ws0   = (short*)d_ws;
    short* x_bf  = ws0;
    short* o_bf  = ws0;
    short* wat_t = ws0 + (size_t)4 * 1024 * 1024;
    short* wpt_t = ws0 + (size_t)7 * 1024 * 1024;
    short* q_bf  = ws0 + (size_t)8 * 1024 * 1024;
    short* k_bf  = (short*)d_out;
    short* v_bft = k_bf + (size_t)PRES_HALF;

    cast_x_k<<<4096, 256, 0, stream>>>(x, x_bf);
    transpose_k<<<dim3(96, 32), 256, 0, stream>>>(w_attn, 3 * DM, wat_t);
    transpose_k<<<dim3(32, 32), 256, 0, stream>>>(w_proj, DM, wpt_t);

    qkv_mfma_k<<<dim3(24, 32), 256, 0, stream>>>(x_bf, wat_t, b_attn, q_bf, outf,
                                                 k_bf, v_bft);

    attn_mfma6_k<<<dim3(BB * NH * (SS / 64)), 256, 0, stream>>>(q_bf, k_bf, v_bft, o_bf);

    proj_mfma_k<<<dim3(8, 32), 256, 0, stream>>>(o_bf, wpt_t, b_proj, outf);
  } else {
    // ---- legacy fp32-attention fallback ----
    short* x_bf;
    short* q_bf;
    short* wat_t;
    short* wpt_t;
    short* o_bf;
    if (ws_size >= 16 * MB) {
      short* ws = (short*)d_ws;
      x_bf  = (short*)d_out;                 // out0 [0,8MB) dead until proj
      q_bf  = x_bf + OUT_ELEMS;              // out0 [8MB,16MB)
      wat_t = ws;
      wpt_t = wat_t + 3 * DM * DM;
      o_bf  = wat_t + 4 * DM * DM;
    } else {
      x_bf  = (short*)d_out;
      q_bf  = x_bf + OUT_ELEMS;
      wat_t = (short*)d_in[1];
      wpt_t = wat_t + 3 * DM * DM;
      o_bf  = wat_t + 4 * DM * DM;
    }
    cast_x_k<<<4096, 256, 0, stream>>>(x, x_bf);
    transpose_k<<<dim3(96, 32), 256, 0, stream>>>(w_attn, 3 * DM, wat_t);
    transpose_k<<<dim3(32, 32), 256, 0, stream>>>(w_proj, DM, wpt_t);
    qkv_mfma_k<<<dim3(24, 32), 256, 0, stream>>>(x_bf, wat_t, b_attn, q_bf, outf,
                                                 nullptr, nullptr);
    attn_k<<<dim3(BB * NH, SS / 64), 256, 0, stream>>>(q_bf, outf + OUT_ELEMS, o_bf);
    proj_mfma_k<<<dim3(8, 32), 256, 0, stream>>>(o_bf, wpt_t, b_proj, outf);
  }
}

// Round 9
// 236.164 us; speedup vs baseline: 1.1091x; 1.0652x over previous
//
#include <hip/hip_runtime.h>
#include <math.h>

constexpr int BB = 2;
constexpr int SS = 2048;
constexpr int DM = 1024;
constexpr int NH = 16;
constexpr int KD = 64;
constexpr int OUT_ELEMS  = BB*SS*DM;     // 4194304 fp32 (output 0 region)
constexpr int PRES_HALF  = BB*NH*SS*KD;  // 4194304 fp32 (k or v)
#define NEGSENT (-1e30f)

typedef __attribute__((ext_vector_type(8))) short short8;   // 8 x bf16 bits
typedef __attribute__((ext_vector_type(4))) short short4v;  // 4 x bf16 bits
typedef __attribute__((ext_vector_type(4))) float f32x4;

__device__ __forceinline__ float us2f(unsigned short u) {
  union { unsigned int ui; float f; } c; c.ui = ((unsigned int)u) << 16; return c.f;
}
__device__ __forceinline__ short f2s(float f) {
  // round-to-nearest-even bf16 (finite inputs only)
  union { float f; unsigned int u; } c; c.f = f;
  return (short)((c.u + 0x7FFFu + ((c.u >> 16) & 1u)) >> 16);
}

#define GLOAD_LDS16(g, l) \
  __builtin_amdgcn_global_load_lds((const __attribute__((address_space(1))) void*)(g), \
                                   (__attribute__((address_space(3))) void*)(l), 16, 0, 0)

// ---------------- prep: cast x[4096,1024] fp32 -> bf16 ----------------------
__global__ __launch_bounds__(256)
void cast_x_k(const float* __restrict__ x, short* __restrict__ xb) {
  const size_t i = ((size_t)blockIdx.x * 256 + threadIdx.x) * 4;
  const float4 v = *(const float4*)(x + i);
  short4v s; s.x = f2s(v.x); s.y = f2s(v.y); s.z = f2s(v.z); s.w = f2s(v.w);
  *(short4v*)(xb + i) = s;
}

// ---------------- prep: transpose w[1024,N] fp32 -> wT[N,1024] bf16 ---------
__global__ __launch_bounds__(256)
void transpose_k(const float* __restrict__ w, int N, short* __restrict__ wt) {
  __shared__ float tl[32][33];
  const int tx = threadIdx.x & 31, ty = threadIdx.x >> 5;   // 32 x 8
  const int n0 = blockIdx.x * 32, k0 = blockIdx.y * 32;
  #pragma unroll
  for (int i = 0; i < 4; ++i) {
    const int kk = ty + i * 8;
    tl[kk][tx] = w[(size_t)(k0 + kk) * N + n0 + tx];
  }
  __syncthreads();
  #pragma unroll
  for (int i = 0; i < 4; ++i) {
    const int nn = ty + i * 8;
    wt[(size_t)(n0 + nn) * 1024 + k0 + tx] = f2s(tl[tx][nn]);
  }
}

// ---------------- prep: transpose present-v fp32 [bh][s][64] -> bf16 [bh][64][s]
// 64x64 tile via padded LDS; both global sides coalesced (128B per row by
// 4 lanes). LDS read is 2-way aliased (free, m136).
__global__ __launch_bounds__(256)
void v_tr_k(const float* __restrict__ vf, short* __restrict__ vt) {
  __shared__ float tl[64][65];
  const int bh = blockIdx.x;                 // 0..31
  const int s0 = blockIdx.y * 64;            // 32 tiles
  const int tr = threadIdx.x >> 2;           // 0..63
  const int tc = (threadIdx.x & 3) * 16;
  const float* src = vf + ((size_t)bh * SS + s0) * KD;
  #pragma unroll
  for (int i = 0; i < 4; ++i) {
    const float4 v = *(const float4*)(src + (size_t)tr * KD + tc + i * 4);
    tl[tr][tc + i * 4 + 0] = v.x; tl[tr][tc + i * 4 + 1] = v.y;
    tl[tr][tc + i * 4 + 2] = v.z; tl[tr][tc + i * 4 + 3] = v.w;
  }
  __syncthreads();
  short8 o0, o1;
  #pragma unroll
  for (int i = 0; i < 8; ++i) o0[i] = f2s(tl[tc + i][tr]);
  #pragma unroll
  for (int i = 0; i < 8; ++i) o1[i] = f2s(tl[tc + 8 + i][tr]);
  short* dst = vt + ((size_t)bh * KD + tr) * SS + s0 + tc;
  *(short8*)(dst) = o0;
  *(short8*)(dst + 8) = o1;
}

// ---------------- MFMA GEMM core (m97 structure, BK=32 — proven best) -------
__device__ __forceinline__ void mfma_tile_loop(
    const short* __restrict__ A, const short* __restrict__ Bt,
    int m0, int n0, short* Asm, short* Bsm, f32x4 (*acc)[4]) {
  const int tid = threadIdx.x;
  const int lane = tid & 63;
  const int w = tid >> 6;
  const int wm = (w >> 1) * 64, wn = (w & 1) * 64;
  const int ln15 = lane & 15, quad = lane >> 4;
  for (int k0 = 0; k0 < 1024; k0 += 32) {
    #pragma unroll
    for (int j = 0; j < 2; ++j) {
      const int e = j * 256 + tid;          // 0..511
      const int r = e >> 2, cq = e & 3;     // row, 16B-chunk
      GLOAD_LDS16(A  + (size_t)(m0 + r) * 1024 + k0 + cq * 8, Asm + e * 8);
      GLOAD_LDS16(Bt + (size_t)(n0 + r) * 1024 + k0 + cq * 8, Bsm + e * 8);
    }
    __syncthreads();                        // drains vmcnt before barrier
    short8 af[4], bf[4];
    #pragma unroll
    for (int t = 0; t < 4; ++t)
      af[t] = *(const short8*)(Asm + (wm + t * 16 + ln15) * 32 + quad * 8);
    #pragma unroll
    for (int t = 0; t < 4; ++t)
      bf[t] = *(const short8*)(Bsm + (wn + t * 16 + ln15) * 32 + quad * 8);
    #pragma unroll
    for (int tm = 0; tm < 4; ++tm)
      #pragma unroll
      for (int tn = 0; tn < 4; ++tn)
        acc[tm][tn] = __builtin_amdgcn_mfma_f32_16x16x32_bf16(
            af[tm], bf[tn], acc[tm][tn], 0, 0, 0);
    __syncthreads();
  }
}

// ---------------- QKV GEMM: routes v,q,k = split(qkv) ----------------------
//   n in [0,1024)    -> v fp32 -> outf[8M..12M) = present[1]
//   n in [1024,2048) -> q bf16 -> qbf [B,H,S,KD]
//   n in [2048,3072) -> k fp32 -> outf[4M..8M)  = present[0]; + bf16 K
// (V^T bf16 is produced by v_tr_k — scatter removed from this epilogue.)
__global__ __launch_bounds__(256)
void qkv_mfma_k(const short* __restrict__ A, const short* __restrict__ Bt,
                const float* __restrict__ bias, short* __restrict__ qbf,
                float* __restrict__ outf, short* __restrict__ kbf) {
  __shared__ short Asm[128 * 32];
  __shared__ short Bsm[128 * 32];
  const int n0 = blockIdx.x * 128, m0 = blockIdx.y * 128;
  f32x4 acc[4][4] = {};
  mfma_tile_loop(A, Bt, m0, n0, Asm, Bsm, acc);
  const int lane = threadIdx.x & 63;
  const int w = threadIdx.x >> 6;
  const int wm = (w >> 1) * 64, wn = (w & 1) * 64;
  const int col = lane & 15, row4 = (lane >> 4) * 4;
  #pragma unroll
  for (int tm = 0; tm < 4; ++tm) {
    #pragma unroll
    for (int tn = 0; tn < 4; ++tn) {
      const int n = n0 + wn + tn * 16 + col;
      #pragma unroll
      for (int r = 0; r < 4; ++r) {
        const int m = m0 + wm + tm * 16 + row4 + r;
        const float val = acc[tm][tn][r] + bias[n];
        const int bb = m >> 11, s = m & 2047;
        const int c = n & 1023, h = c >> 6, d = c & 63;
        const size_t idx = ((size_t)(bb * NH + h) * SS + s) * KD + d;
        if (n < DM) {
          outf[(size_t)OUT_ELEMS + (size_t)PRES_HALF + idx] = val;   // v fp32
        } else if (n < 2 * DM) {
          qbf[idx] = f2s(val);                                        // q bf16
        } else {
          outf[(size_t)OUT_ELEMS + idx] = val;                        // k fp32
          if (kbf) kbf[idx] = f2s(val);
        }
      }
    }
  }
}

// ---------------- Output projection: o @ w_projT + b -> out0 fp32 -----------
__global__ __launch_bounds__(256)
void proj_mfma_k(const short* __restrict__ A, const short* __restrict__ Bt,
                 const float* __restrict__ bias, float* __restrict__ outf) {
  __shared__ short Asm[128 * 32];
  __shared__ short Bsm[128 * 32];
  const int n0 = blockIdx.x * 128, m0 = blockIdx.y * 128;
  f32x4 acc[4][4] = {};
  mfma_tile_loop(A, Bt, m0, n0, Asm, Bsm, acc);
  const int lane = threadIdx.x & 63;
  const int w = threadIdx.x >> 6;
  const int wm = (w >> 1) * 64, wn = (w & 1) * 64;
  const int col = lane & 15, row4 = (lane >> 4) * 4;
  #pragma unroll
  for (int tm = 0; tm < 4; ++tm) {
    #pragma unroll
    for (int tn = 0; tn < 4; ++tn) {
      const int n = n0 + wn + tn * 16 + col;
      const float b = bias[n];
      #pragma unroll
      for (int r = 0; r < 4; ++r) {
        const int m = m0 + wm + tm * 16 + row4 + r;
        outf[(size_t)m * DM + n] = acc[tm][tn][r] + b;
      }
    }
  }
}

// ---------------- staging: one 64-key chunk of K + V^T, 256 threads ---------
__device__ __forceinline__ void stage_kv4(const short* __restrict__ Kg,
                                          const short* __restrict__ Vg,
                                          int kb, short* Ksb, short* Vtb,
                                          int tid) {
  #pragma unroll
  for (int rd = 0; rd < 2; ++rd) {
    const int i = rd * 256 + tid;        // 0..511 : row = i>>3, grp = i&7
    const int row = i >> 3, grp = i & 7;
    const int sw = (grp ^ (row & 7)) << 3;
    GLOAD_LDS16(Kg + (size_t)(kb + row) * KD + sw, Ksb + i * 8);
    GLOAD_LDS16(Vg + (size_t)row * SS + kb + sw, Vtb + i * 8);
  }
}

// ---------------- MFMA causal flash attention, uniform 2-pass blocks --------
// Block = 4 waves, processes the causal PAIR {p, 31-p} of 64-row q-tiles
// SEQUENTIALLY -> every block is exactly 33 chunk-iterations. 512 blocks =
// 2/CU (80 KB LDS), co-resident for the whole kernel, finish simultaneously:
// fixes R8's occupancy decay (4 unequal blocks/CU -> long block ran alone).
// Inner loop = R8 structure: K/V dbuf prefetch, T13 defer-max, fma-folded
// exp2 P-compute, swizzled LDS (0 conflicts).
__global__ __launch_bounds__(256)
void attn_mfma7_k(const short* __restrict__ qbf, const short* __restrict__ kbf,
                  const short* __restrict__ vbft, short* __restrict__ obf) {
  __shared__ short Ks[2][64 * 64];    // K chunk  [key][d], swizzled
  __shared__ short Vt[2][64 * 64];    // V^T chunk [d][key], swizzled
  __shared__ short Ps[4][16 * 64];    // per-wave P [qrow][key], swizzled
  const int bid = blockIdx.x;                     // 0..511
  const int xcd = bid & 7, g = bid >> 3;          // g 0..63
  const int rnd = g >> 4;                         // head-in-XCD 0..3
  const int p   = g & 15;                         // causal pair 0..15
  const int bh  = (xcd << 2) | rnd;
  const int tid = threadIdx.x;
  const int w   = tid >> 6;
  const int lane = tid & 63;
  const int ln15 = lane & 15, quad = lane >> 4;
  const int rswz = (ln15 & 7) << 3;               // fragment-read swizzle
  const float SC2 = 0.125f * 1.44269504f;         // scale * log2(e)
  const float THR = 8.0f;                         // defer-max threshold (raw)

  const short* Kg = kbf  + (size_t)bh * SS * KD;
  const short* Vg = vbft + (size_t)bh * KD * SS;
  short* Pw = Ps[w];
  const int bb = bh >> 4, h = bh & 15;

  #pragma unroll 1
  for (int pass = 0; pass < 2; ++pass) {
    const int qb = pass ? (31 - p) : p;
    const int q0 = qb * 64;
    const int nch = qb + 1;

    // Q fragments for this wave's 16 rows: row = ln15, k = kt*32 + quad*8
    short8 aq[2];
    {
      const short* qp = qbf + ((size_t)bh * SS + q0 + w * 16) * KD;
      aq[0] = *(const short8*)(qp + (size_t)ln15 * KD + quad * 8);
      aq[1] = *(const short8*)(qp + (size_t)ln15 * KD + 32 + quad * 8);
    }
    f32x4 O[4] = {};                    // [tn], rows quad*4+r
    float mreg[4], lreg[4];             // [r]
    #pragma unroll
    for (int r = 0; r < 4; ++r) { mreg[r] = NEGSENT; lreg[r] = 0.f; }

    stage_kv4(Kg, Vg, 0, Ks[0], Vt[0], tid);   // chunk 0 -> buf 0
    __syncthreads();

    for (int ch = 0; ch < nch; ++ch) {
      const int cur = ch & 1;
      if (ch + 1 < nch)                        // issue next-chunk loads first
        stage_kv4(Kg, Vg, (ch + 1) * 64, Ks[cur ^ 1], Vt[cur ^ 1], tid);
      const short* Kc = Ks[cur];
      const short* Vc = Vt[cur];

      // ---- QK^T: S[16 q][64 k] ----
      f32x4 S[4] = {};
      #pragma unroll
      for (int kt = 0; kt < 2; ++kt) {
        short8 bk[4];
        #pragma unroll
        for (int tn = 0; tn < 4; ++tn)
          bk[tn] = *(const short8*)(Kc + (tn * 16 + ln15) * 64 + ((kt * 32 + quad * 8) ^ rswz));
        #pragma unroll
        for (int tn = 0; tn < 4; ++tn)
          S[tn] = __builtin_amdgcn_mfma_f32_16x16x32_bf16(aq[kt], bk[tn], S[tn], 0, 0, 0);
      }

      // ---- causal mask on the diagonal chunk ----
      if (ch == qb) {
        const int rowl = w * 16 + quad * 4;
        #pragma unroll
        for (int tn = 0; tn < 4; ++tn) {
          const int colk = tn * 16 + ln15;
          #pragma unroll
          for (int r = 0; r < 4; ++r)
            if (colk > rowl + r) S[tn][r] = NEGSENT;
        }
      }

      // ---- row max (max3-friendly tree + 4-step shfl reduce) ----
      float pmax[4];
      #pragma unroll
      for (int r = 0; r < 4; ++r) {
        float mx = fmaxf(fmaxf(fmaxf(S[0][r], S[1][r]), S[2][r]), S[3][r]);
        mx = fmaxf(mx, __shfl_xor(mx, 1, 64));
        mx = fmaxf(mx, __shfl_xor(mx, 2, 64));
        mx = fmaxf(mx, __shfl_xor(mx, 4, 64));
        mx = fmaxf(mx, __shfl_xor(mx, 8, 64));
        pmax[r] = mx;
      }

      // ---- T13 defer-max: rescale only when some row grew past THR ----
      bool okl = true;
      #pragma unroll
      for (int r = 0; r < 4; ++r) okl = okl && (pmax[r] - mreg[r] <= THR);
      if (!__all((int)okl)) {                 // wave-uniform branch
        #pragma unroll
        for (int r = 0; r < 4; ++r) {
          const float mn = fmaxf(mreg[r], pmax[r]);
          const float al = exp2f((mreg[r] - mn) * SC2);
          mreg[r] = mn;
          lreg[r] *= al;
          O[0][r] *= al; O[1][r] *= al; O[2][r] *= al; O[3][r] *= al;
        }
      }

      // ---- P = exp2(fma(S,SC2,-m*SC2)); accumulate l; write P (swizzled) ----
      #pragma unroll
      for (int r = 0; r < 4; ++r) {
        const float mnsc = mreg[r] * SC2;
        const int prow = quad * 4 + r;
        const int rs = (prow & 7) << 3;
        float p0 = exp2f(fmaf(S[0][r], SC2, -mnsc));
        float p1 = exp2f(fmaf(S[1][r], SC2, -mnsc));
        float p2 = exp2f(fmaf(S[2][r], SC2, -mnsc));
        float p3 = exp2f(fmaf(S[3][r], SC2, -mnsc));
        lreg[r] += (p0 + p1) + (p2 + p3);
        Pw[prow * 64 + ((0 * 16 + ln15) ^ rs)] = f2s(p0);
        Pw[prow * 64 + ((1 * 16 + ln15) ^ rs)] = f2s(p1);
        Pw[prow * 64 + ((2 * 16 + ln15) ^ rs)] = f2s(p2);
        Pw[prow * 64 + ((3 * 16 + ln15) ^ rs)] = f2s(p3);
      }
      asm volatile("s_waitcnt lgkmcnt(0)" ::: "memory");  // own P writes landed
      __builtin_amdgcn_sched_barrier(0);                  // rule 18

      // ---- PV: O += P @ V ----
      #pragma unroll
      for (int kt = 0; kt < 2; ++kt) {
        short8 ap = *(const short8*)(Pw + ln15 * 64 + ((kt * 32 + quad * 8) ^ rswz));
        short8 bv[4];
        #pragma unroll
        for (int tn = 0; tn < 4; ++tn)
          bv[tn] = *(const short8*)(Vc + (tn * 16 + ln15) * 64 + ((kt * 32 + quad * 8) ^ rswz));
        #pragma unroll
        for (int tn = 0; tn < 4; ++tn)
          O[tn] = __builtin_amdgcn_mfma_f32_16x16x32_bf16(ap, bv[tn], O[tn], 0, 0, 0);
      }
      __syncthreads();   // next buf staged+visible; prev reads done
    }

    // ---- finalize l and write o token-major (no LDS access) ----
    #pragma unroll
    for (int r = 0; r < 4; ++r) {
      float l = lreg[r];
      l += __shfl_xor(l, 1, 64);
      l += __shfl_xor(l, 2, 64);
      l += __shfl_xor(l, 4, 64);
      l += __shfl_xor(l, 8, 64);
      lreg[r] = 1.f / fmaxf(l, 1e-30f);
    }
    short* ob = obf + ((size_t)bb * SS + q0 + w * 16) * DM + h * KD;
    #pragma unroll
    for (int tn = 0; tn < 4; ++tn)
      #pragma unroll
      for (int r = 0; r < 4; ++r)
        ob[(size_t)(quad * 4 + r) * DM + tn * 16 + ln15] = f2s(O[tn][r] * lreg[r]);
    // next pass restages buf0 after everyone's final barrier of this pass;
    // epilogue touches no LDS, so no extra sync needed.
  }
}

// ---------------- legacy fp32 flash attention (fallback, small ws) ----------
__global__ __launch_bounds__(256)
void attn_k(const short* __restrict__ qbf, const float* __restrict__ pres,
            short* __restrict__ obf) {
  __shared__ float Ksf[32][64];
  __shared__ float Vsf[32][64];
  const int bh = blockIdx.x;
  const int q0 = ((int)gridDim.y - 1 - (int)blockIdx.y) * 64;
  const int t  = threadIdx.x;
  const int part = t & 3;
  const int row  = t >> 2;
  const int qr   = q0 + row;
  const int dbase = part * 16;
  const size_t qoff = ((size_t)bh * SS + qr) * KD + dbase;
  float q[16], o[16];
  #pragma unroll
  for (int i = 0; i < 16; ++i) q[i] = us2f((unsigned short)qbf[qoff + i]);
  #pragma unroll
  for (int i = 0; i < 16; ++i) o[i] = 0.f;
  float m = NEGSENT, l = 0.f;
  const float* Kb = pres + (size_t)bh * SS * KD;
  const float* Vb = pres + (size_t)PRES_HALF + (size_t)bh * SS * KD;
  const int nch = (q0 + 64) / 32;
  for (int ch = 0; ch < nch; ++ch) {
    const int kbase = ch * 32;
    __syncthreads();
    {
      const float4* ksrc = (const float4*)(Kb + (size_t)kbase * KD);
      const float4* vsrc = (const float4*)(Vb + (size_t)kbase * KD);
      float4* kdst = (float4*)&Ksf[0][0];
      float4* vdst = (float4*)&Vsf[0][0];
      #pragma unroll
      for (int i = 0; i < 2; ++i) {
        kdst[t + i * 256] = ksrc[t + i * 256];
        vdst[t + i * 256] = vsrc[t + i * 256];
      }
    }
    __syncthreads();
    float sc[32];
    #pragma unroll
    for (int kk = 0; kk < 32; ++kk) {
      float s = 0.f;
      #pragma unroll
      for (int i = 0; i < 16; ++i) s = fmaf(q[i], Ksf[kk][dbase + i], s);
      s += __shfl_xor(s, 1, 64);
      s += __shfl_xor(s, 2, 64);
      sc[kk] = (kbase + kk <= qr) ? s * 0.125f : NEGSENT;
    }
    float mc = sc[0];
    #pragma unroll
    for (int kk = 1; kk < 32; ++kk) mc = fmaxf(mc, sc[kk]);
    const float mn = fmaxf(m, mc);
    const float alpha = __expf(m - mn);
    l *= alpha;
    #pragma unroll
    for (int i = 0; i < 16; ++i) o[i] *= alpha;
    #pragma unroll
    for (int kk = 0; kk < 32; ++kk) {
      const float p = __expf(sc[kk] - mn);
      l += p;
      #pragma unroll
      for (int i = 0; i < 16; ++i) o[i] = fmaf(p, Vsf[kk][dbase + i], o[i]);
    }
    m = mn;
  }
  const float inv = 1.f / fmaxf(l, 1e-30f);
  const int bb = bh >> 4, h = bh & 15;
  const size_t ooff = ((size_t)(bb * SS + qr)) * DM + h * KD + dbase;
  #pragma unroll
  for (int i = 0; i < 16; ++i) obf[ooff + i] = f2s(o[i] * inv);
}

extern "C" void kernel_launch(void* const* d_in, const int* in_sizes, int n_in,
                              void* d_out, int out_size, void* d_ws, size_t ws_size,
                              hipStream_t stream) {
  const float* x      = (const float*)d_in[0];
  const float* w_attn = (const float*)d_in[2];
  const float* b_attn = (const float*)d_in[3];
  const float* w_proj = (const float*)d_in[4];
  const float* b_proj = (const float*)d_in[5];
  float* outf = (float*)d_out;   // fp32: [out0 4M | k 4M | v 4M] elements

  constexpr size_t MB = 1024 * 1024;
  if (ws_size >= 24 * MB) {
    // ---- MFMA-attention path ----
    // ws (shorts): [0,4M) x_bf then o_bf (lifetimes disjoint) |
    //              [4M,7M) w_attn_T | [7M,8M) w_proj_T | [8M,12M) q_bf
    // d_out out0 region (dead until proj): [0,4M) k_bf | [4M,8M) v_bfT
    short* ws0   = (short*)d_ws;
    short* x_bf  = ws0;
    short* o_bf  = ws0;
    short* wat_t = ws0 + (size_t)4 * 1024 * 1024;
    short* wpt_t = ws0 + (size_t)7 * 1024 * 1024;
    short* q_bf  = ws0 + (size_t)8 * 1024 * 1024;
    short* k_bf  = (short*)d_out;
    short* v_bft = k_bf + (size_t)PRES_HALF;

    cast_x_k<<<4096, 256, 0, stream>>>(x, x_bf);
    transpose_k<<<dim3(96, 32), 256, 0, stream>>>(w_attn, 3 * DM, wat_t);
    transpose_k<<<dim3(32, 32), 256, 0, stream>>>(w_proj, DM, wpt_t);

    qkv_mfma_k<<<dim3(24, 32), 256, 0, stream>>>(x_bf, wat_t, b_attn, q_bf, outf,
                                                 k_bf);

    v_tr_k<<<dim3(BB * NH, SS / 64), 256, 0, stream>>>(
        outf + OUT_ELEMS + PRES_HALF, v_bft);

    attn_mfma7_k<<<dim3(512), 256, 0, stream>>>(q_bf, k_bf, v_bft, o_bf);

    proj_mfma_k<<<dim3(8, 32), 256, 0, stream>>>(o_bf, wpt_t, b_proj, outf);
  } else {
    // ---- legacy fp32-attention fallback ----
    short* x_bf;
    short* q_bf;
    short* wat_t;
    short* wpt_t;
    short* o_bf;
    if (ws_size >= 16 * MB) {
      short* ws = (short*)d_ws;
      x_bf  = (short*)d_out;                 // out0 [0,8MB) dead until proj
      q_bf  = x_bf + OUT_ELEMS;              // out0 [8MB,16MB)
      wat_t = ws;
      wpt_t = wat_t + 3 * DM * DM;
      o_bf  = wat_t + 4 * DM * DM;
    } else {
      x_bf  = (short*)d_out;
      q_bf  = x_bf + OUT_ELEMS;
      wat_t = (short*)d_in[1];
      wpt_t = wat_t + 3 * DM * DM;
      o_bf  = wat_t + 4 * DM * DM;
    }
    cast_x_k<<<4096, 256, 0, stream>>>(x, x_bf);
    transpose_k<<<dim3(96, 32), 256, 0, stream>>>(w_attn, 3 * DM, wat_t);
    transpose_k<<<dim3(32, 32), 256, 0, stream>>>(w_proj, DM, wpt_t);
    qkv_mfma_k<<<dim3(24, 32), 256, 0, stream>>>(x_bf, wat_t, b_attn, q_bf, outf,
                                                 nullptr);
    attn_k<<<dim3(BB * NH, SS / 64), 256, 0, stream>>>(q_bf, outf + OUT_ELEMS, o_bf);
    proj_mfma_k<<<dim3(8, 32), 256, 0, stream>>>(o_bf, wpt_t, b_proj, outf);
  }
}

// Round 10
// 226.720 us; speedup vs baseline: 1.1553x; 1.0417x over previous
//
#include <hip/hip_runtime.h>
#include <math.h>

constexpr int BB = 2;
constexpr int SS = 2048;
constexpr int DM = 1024;
constexpr int NH = 16;
constexpr int KD = 64;
constexpr int OUT_ELEMS  = BB*SS*DM;     // 4194304 fp32 (output 0 region)
constexpr int PRES_HALF  = BB*NH*SS*KD;  // 4194304 fp32 (k or v)
#define NEGSENT (-1e30f)

typedef __attribute__((ext_vector_type(8))) short short8;   // 8 x bf16 bits
typedef __attribute__((ext_vector_type(4))) short short4v;  // 4 x bf16 bits
typedef __attribute__((ext_vector_type(4))) float f32x4;

__device__ __forceinline__ float us2f(unsigned short u) {
  union { unsigned int ui; float f; } c; c.ui = ((unsigned int)u) << 16; return c.f;
}
__device__ __forceinline__ short f2s(float f) {
  // round-to-nearest-even bf16 (finite inputs only) — software path
  union { float f; unsigned int u; } c; c.f = f;
  return (short)((c.u + 0x7FFFu + ((c.u >> 16) & 1u)) >> 16);
}
__device__ __forceinline__ short f2s_hw(float f) {
  // hardware RNE bf16 via v_cvt_pk_bf16_f32 (no builtin on gfx950 — T12).
  // Single instruction vs ~3-4 VALU for the manual rounding.
  unsigned int r;
  asm("v_cvt_pk_bf16_f32 %0, %1, %1" : "=v"(r) : "v"(f));
  return (short)r;   // ds_write_b16 takes low 16 bits; mask elided
}

#define GLOAD_LDS16(g, l) \
  __builtin_amdgcn_global_load_lds((const __attribute__((address_space(1))) void*)(g), \
                                   (__attribute__((address_space(3))) void*)(l), 16, 0, 0)

// ---------------- prep: cast x[4096,1024] fp32 -> bf16 ----------------------
__global__ __launch_bounds__(256)
void cast_x_k(const float* __restrict__ x, short* __restrict__ xb) {
  const size_t i = ((size_t)blockIdx.x * 256 + threadIdx.x) * 4;
  const float4 v = *(const float4*)(x + i);
  short4v s; s.x = f2s(v.x); s.y = f2s(v.y); s.z = f2s(v.z); s.w = f2s(v.w);
  *(short4v*)(xb + i) = s;
}

// ---------------- prep: transpose w[1024,N] fp32 -> wT[N,1024] bf16 ---------
__global__ __launch_bounds__(256)
void transpose_k(const float* __restrict__ w, int N, short* __restrict__ wt) {
  __shared__ float tl[32][33];
  const int tx = threadIdx.x & 31, ty = threadIdx.x >> 5;   // 32 x 8
  const int n0 = blockIdx.x * 32, k0 = blockIdx.y * 32;
  #pragma unroll
  for (int i = 0; i < 4; ++i) {
    const int kk = ty + i * 8;
    tl[kk][tx] = w[(size_t)(k0 + kk) * N + n0 + tx];
  }
  __syncthreads();
  #pragma unroll
  for (int i = 0; i < 4; ++i) {
    const int nn = ty + i * 8;
    wt[(size_t)(n0 + nn) * 1024 + k0 + tx] = f2s(tl[tx][nn]);
  }
}

// ---------------- prep: transpose present-v fp32 [bh][s][64] -> bf16 [bh][64][s]
__global__ __launch_bounds__(256)
void v_tr_k(const float* __restrict__ vf, short* __restrict__ vt) {
  __shared__ float tl[64][65];
  const int bh = blockIdx.x;                 // 0..31
  const int s0 = blockIdx.y * 64;            // 32 tiles
  const int tr = threadIdx.x >> 2;           // 0..63
  const int tc = (threadIdx.x & 3) * 16;
  const float* src = vf + ((size_t)bh * SS + s0) * KD;
  #pragma unroll
  for (int i = 0; i < 4; ++i) {
    const float4 v = *(const float4*)(src + (size_t)tr * KD + tc + i * 4);
    tl[tr][tc + i * 4 + 0] = v.x; tl[tr][tc + i * 4 + 1] = v.y;
    tl[tr][tc + i * 4 + 2] = v.z; tl[tr][tc + i * 4 + 3] = v.w;
  }
  __syncthreads();
  short8 o0, o1;
  #pragma unroll
  for (int i = 0; i < 8; ++i) o0[i] = f2s(tl[tc + i][tr]);
  #pragma unroll
  for (int i = 0; i < 8; ++i) o1[i] = f2s(tl[tc + 8 + i][tr]);
  short* dst = vt + ((size_t)bh * KD + tr) * SS + s0 + tc;
  *(short8*)(dst) = o0;
  *(short8*)(dst + 8) = o1;
}

// ---------------- MFMA GEMM core (m97 structure, BK=32 — proven best) -------
__device__ __forceinline__ void mfma_tile_loop(
    const short* __restrict__ A, const short* __restrict__ Bt,
    int m0, int n0, short* Asm, short* Bsm, f32x4 (*acc)[4]) {
  const int tid = threadIdx.x;
  const int lane = tid & 63;
  const int w = tid >> 6;
  const int wm = (w >> 1) * 64, wn = (w & 1) * 64;
  const int ln15 = lane & 15, quad = lane >> 4;
  for (int k0 = 0; k0 < 1024; k0 += 32) {
    #pragma unroll
    for (int j = 0; j < 2; ++j) {
      const int e = j * 256 + tid;          // 0..511
      const int r = e >> 2, cq = e & 3;     // row, 16B-chunk
      GLOAD_LDS16(A  + (size_t)(m0 + r) * 1024 + k0 + cq * 8, Asm + e * 8);
      GLOAD_LDS16(Bt + (size_t)(n0 + r) * 1024 + k0 + cq * 8, Bsm + e * 8);
    }
    __syncthreads();                        // drains vmcnt before barrier
    short8 af[4], bf[4];
    #pragma unroll
    for (int t = 0; t < 4; ++t)
      af[t] = *(const short8*)(Asm + (wm + t * 16 + ln15) * 32 + quad * 8);
    #pragma unroll
    for (int t = 0; t < 4; ++t)
      bf[t] = *(const short8*)(Bsm + (wn + t * 16 + ln15) * 32 + quad * 8);
    #pragma unroll
    for (int tm = 0; tm < 4; ++tm)
      #pragma unroll
      for (int tn = 0; tn < 4; ++tn)
        acc[tm][tn] = __builtin_amdgcn_mfma_f32_16x16x32_bf16(
            af[tm], bf[tn], acc[tm][tn], 0, 0, 0);
    __syncthreads();
  }
}

// ---------------- QKV GEMM: routes v,q,k = split(qkv) ----------------------
//   n in [0,1024)    -> v fp32 -> outf[8M..12M) = present[1]
//   n in [1024,2048) -> q bf16 -> qbf [B,H,S,KD]
//   n in [2048,3072) -> k fp32 -> outf[4M..8M)  = present[0]; + bf16 K
__global__ __launch_bounds__(256)
void qkv_mfma_k(const short* __restrict__ A, const short* __restrict__ Bt,
                const float* __restrict__ bias, short* __restrict__ qbf,
                float* __restrict__ outf, short* __restrict__ kbf) {
  __shared__ short Asm[128 * 32];
  __shared__ short Bsm[128 * 32];
  const int n0 = blockIdx.x * 128, m0 = blockIdx.y * 128;
  f32x4 acc[4][4] = {};
  mfma_tile_loop(A, Bt, m0, n0, Asm, Bsm, acc);
  const int lane = threadIdx.x & 63;
  const int w = threadIdx.x >> 6;
  const int wm = (w >> 1) * 64, wn = (w & 1) * 64;
  const int col = lane & 15, row4 = (lane >> 4) * 4;
  #pragma unroll
  for (int tm = 0; tm < 4; ++tm) {
    #pragma unroll
    for (int tn = 0; tn < 4; ++tn) {
      const int n = n0 + wn + tn * 16 + col;
      #pragma unroll
      for (int r = 0; r < 4; ++r) {
        const int m = m0 + wm + tm * 16 + row4 + r;
        const float val = acc[tm][tn][r] + bias[n];
        const int bb = m >> 11, s = m & 2047;
        const int c = n & 1023, h = c >> 6, d = c & 63;
        const size_t idx = ((size_t)(bb * NH + h) * SS + s) * KD + d;
        if (n < DM) {
          outf[(size_t)OUT_ELEMS + (size_t)PRES_HALF + idx] = val;   // v fp32
        } else if (n < 2 * DM) {
          qbf[idx] = f2s(val);                                        // q bf16
        } else {
          outf[(size_t)OUT_ELEMS + idx] = val;                        // k fp32
          if (kbf) kbf[idx] = f2s(val);
        }
      }
    }
  }
}

// ---------------- Output projection: o @ w_projT + b -> out0 fp32 -----------
__global__ __launch_bounds__(256)
void proj_mfma_k(const short* __restrict__ A, const short* __restrict__ Bt,
                 const float* __restrict__ bias, float* __restrict__ outf) {
  __shared__ short Asm[128 * 32];
  __shared__ short Bsm[128 * 32];
  const int n0 = blockIdx.x * 128, m0 = blockIdx.y * 128;
  f32x4 acc[4][4] = {};
  mfma_tile_loop(A, Bt, m0, n0, Asm, Bsm, acc);
  const int lane = threadIdx.x & 63;
  const int w = threadIdx.x >> 6;
  const int wm = (w >> 1) * 64, wn = (w & 1) * 64;
  const int col = lane & 15, row4 = (lane >> 4) * 4;
  #pragma unroll
  for (int tm = 0; tm < 4; ++tm) {
    #pragma unroll
    for (int tn = 0; tn < 4; ++tn) {
      const int n = n0 + wn + tn * 16 + col;
      const float b = bias[n];
      #pragma unroll
      for (int r = 0; r < 4; ++r) {
        const int m = m0 + wm + tm * 16 + row4 + r;
        outf[(size_t)m * DM + n] = acc[tm][tn][r] + b;
      }
    }
  }
}

// ---------------- staging: one 64-key chunk of K + V^T, 256 threads ---------
__device__ __forceinline__ void stage_kv4(const short* __restrict__ Kg,
                                          const short* __restrict__ Vg,
                                          int kb, short* Ksb, short* Vtb,
                                          int tid) {
  #pragma unroll
  for (int rd = 0; rd < 2; ++rd) {
    const int i = rd * 256 + tid;        // 0..511 : row = i>>3, grp = i&7
    const int row = i >> 3, grp = i & 7;
    const int sw = (grp ^ (row & 7)) << 3;
    GLOAD_LDS16(Kg + (size_t)(kb + row) * KD + sw, Ksb + i * 8);
    GLOAD_LDS16(Vg + (size_t)row * SS + kb + sw, Vtb + i * 8);
  }
}

// ---------------- MFMA causal flash attention (R9 structure + VALU cuts) ----
// Uniform 2-pass pair blocks (R9). New this round:
//  (a) hardware bf16 convert (v_cvt_pk_bf16_f32) for P and O — 1 VALU/value
//      vs 3-4 for the manual RNE;
//  (b) per-lane conservative defer-max check (20 VALU, no shfl) — full
//      per-row shfl-reduced max only in the rare rescale slow path.
//      Conservative => triggers a superset of rescales; algebra exact.
__global__ __launch_bounds__(256)
void attn_mfma8_k(const short* __restrict__ qbf, const short* __restrict__ kbf,
                  const short* __restrict__ vbft, short* __restrict__ obf) {
  __shared__ short Ks[2][64 * 64];    // K chunk  [key][d], swizzled
  __shared__ short Vt[2][64 * 64];    // V^T chunk [d][key], swizzled
  __shared__ short Ps[4][16 * 64];    // per-wave P [qrow][key], swizzled
  const int bid = blockIdx.x;                     // 0..511
  const int xcd = bid & 7, g = bid >> 3;          // g 0..63
  const int rnd = g >> 4;                         // head-in-XCD 0..3
  const int p   = g & 15;                         // causal pair 0..15
  const int bh  = (xcd << 2) | rnd;
  const int tid = threadIdx.x;
  const int w   = tid >> 6;
  const int lane = tid & 63;
  const int ln15 = lane & 15, quad = lane >> 4;
  const int rswz = (ln15 & 7) << 3;               // fragment-read swizzle
  const float SC2 = 0.125f * 1.44269504f;         // scale * log2(e)
  const float THR = 8.0f;                         // defer-max threshold (raw)

  const short* Kg = kbf  + (size_t)bh * SS * KD;
  const short* Vg = vbft + (size_t)bh * KD * SS;
  short* Pw = Ps[w];
  const int bb = bh >> 4, h = bh & 15;

  #pragma unroll 1
  for (int pass = 0; pass < 2; ++pass) {
    const int qb = pass ? (31 - p) : p;
    const int q0 = qb * 64;
    const int nch = qb + 1;

    // Q fragments for this wave's 16 rows: row = ln15, k = kt*32 + quad*8
    short8 aq[2];
    {
      const short* qp = qbf + ((size_t)bh * SS + q0 + w * 16) * KD;
      aq[0] = *(const short8*)(qp + (size_t)ln15 * KD + quad * 8);
      aq[1] = *(const short8*)(qp + (size_t)ln15 * KD + 32 + quad * 8);
    }
    f32x4 O[4] = {};                    // [tn], rows quad*4+r
    float mreg[4], lreg[4];             // [r]
    #pragma unroll
    for (int r = 0; r < 4; ++r) { mreg[r] = NEGSENT; lreg[r] = 0.f; }

    stage_kv4(Kg, Vg, 0, Ks[0], Vt[0], tid);   // chunk 0 -> buf 0
    __syncthreads();

    for (int ch = 0; ch < nch; ++ch) {
      const int cur = ch & 1;
      if (ch + 1 < nch)                        // issue next-chunk loads first
        stage_kv4(Kg, Vg, (ch + 1) * 64, Ks[cur ^ 1], Vt[cur ^ 1], tid);
      const short* Kc = Ks[cur];
      const short* Vc = Vt[cur];

      // ---- QK^T: S[16 q][64 k] ----
      f32x4 S[4] = {};
      #pragma unroll
      for (int kt = 0; kt < 2; ++kt) {
        short8 bk[4];
        #pragma unroll
        for (int tn = 0; tn < 4; ++tn)
          bk[tn] = *(const short8*)(Kc + (tn * 16 + ln15) * 64 + ((kt * 32 + quad * 8) ^ rswz));
        #pragma unroll
        for (int tn = 0; tn < 4; ++tn)
          S[tn] = __builtin_amdgcn_mfma_f32_16x16x32_bf16(aq[kt], bk[tn], S[tn], 0, 0, 0);
      }

      // ---- causal mask on the diagonal chunk ----
      if (ch == qb) {
        const int rowl = w * 16 + quad * 4;
        #pragma unroll
        for (int tn = 0; tn < 4; ++tn) {
          const int colk = tn * 16 + ln15;
          #pragma unroll
          for (int r = 0; r < 4; ++r)
            if (colk > rowl + r) S[tn][r] = NEGSENT;
        }
      }

      // ---- cheap per-lane defer-max check (conservative, no shfl) ----
      // lane_max(16 S vals) - lane_min(4 mreg) <= THR  =>  every row's
      // pmax - mreg <= THR (proof: per-row portion <= lane_max, mreg >= min)
      {
        float lmax = S[0][0];
        #pragma unroll
        for (int tn = 0; tn < 4; ++tn)
          #pragma unroll
          for (int r = 0; r < 4; ++r) lmax = fmaxf(lmax, S[tn][r]);
        const float mmin = fminf(fminf(mreg[0], mreg[1]), fminf(mreg[2], mreg[3]));
        const bool ok = (lmax - mmin) <= THR;
        if (!__all((int)ok)) {                  // rare slow path: full rescale
          #pragma unroll
          for (int r = 0; r < 4; ++r) {
            float mx = fmaxf(fmaxf(fmaxf(S[0][r], S[1][r]), S[2][r]), S[3][r]);
            mx = fmaxf(mx, __shfl_xor(mx, 1, 64));
            mx = fmaxf(mx, __shfl_xor(mx, 2, 64));
            mx = fmaxf(mx, __shfl_xor(mx, 4, 64));
            mx = fmaxf(mx, __shfl_xor(mx, 8, 64));
            const float mn = fmaxf(mreg[r], mx);
            const float al = exp2f((mreg[r] - mn) * SC2);
            mreg[r] = mn;
            lreg[r] *= al;
            O[0][r] *= al; O[1][r] *= al; O[2][r] *= al; O[3][r] *= al;
          }
        }
      }

      // ---- P = exp2(fma(S,SC2,-m*SC2)); accumulate l; write P (swizzled,
      //      hardware cvt) ----
      #pragma unroll
      for (int r = 0; r < 4; ++r) {
        const float mnsc = mreg[r] * SC2;
        const int prow = quad * 4 + r;
        const int rs = (prow & 7) << 3;
        float p0 = exp2f(fmaf(S[0][r], SC2, -mnsc));
        float p1 = exp2f(fmaf(S[1][r], SC2, -mnsc));
        float p2 = exp2f(fmaf(S[2][r], SC2, -mnsc));
        float p3 = exp2f(fmaf(S[3][r], SC2, -mnsc));
        lreg[r] += (p0 + p1) + (p2 + p3);
        Pw[prow * 64 + ((0 * 16 + ln15) ^ rs)] = f2s_hw(p0);
        Pw[prow * 64 + ((1 * 16 + ln15) ^ rs)] = f2s_hw(p1);
        Pw[prow * 64 + ((2 * 16 + ln15) ^ rs)] = f2s_hw(p2);
        Pw[prow * 64 + ((3 * 16 + ln15) ^ rs)] = f2s_hw(p3);
      }
      asm volatile("s_waitcnt lgkmcnt(0)" ::: "memory");  // own P writes landed
      __builtin_amdgcn_sched_barrier(0);                  // rule 18

      // ---- PV: O += P @ V ----
      #pragma unroll
      for (int kt = 0; kt < 2; ++kt) {
        short8 ap = *(const short8*)(Pw + ln15 * 64 + ((kt * 32 + quad * 8) ^ rswz));
        short8 bv[4];
        #pragma unroll
        for (int tn = 0; tn < 4; ++tn)
          bv[tn] = *(const short8*)(Vc + (tn * 16 + ln15) * 64 + ((kt * 32 + quad * 8) ^ rswz));
        #pragma unroll
        for (int tn = 0; tn < 4; ++tn)
          O[tn] = __builtin_amdgcn_mfma_f32_16x16x32_bf16(ap, bv[tn], O[tn], 0, 0, 0);
      }
      __syncthreads();   // next buf staged+visible; prev reads done
    }

    // ---- finalize l and write o token-major (no LDS access) ----
    #pragma unroll
    for (int r = 0; r < 4; ++r) {
      float l = lreg[r];
      l += __shfl_xor(l, 1, 64);
      l += __shfl_xor(l, 2, 64);
      l += __shfl_xor(l, 4, 64);
      l += __shfl_xor(l, 8, 64);
      lreg[r] = 1.f / fmaxf(l, 1e-30f);
    }
    short* ob = obf + ((size_t)bb * SS + q0 + w * 16) * DM + h * KD;
    #pragma unroll
    for (int tn = 0; tn < 4; ++tn)
      #pragma unroll
      for (int r = 0; r < 4; ++r)
        ob[(size_t)(quad * 4 + r) * DM + tn * 16 + ln15] = f2s_hw(O[tn][r] * lreg[r]);
  }
}

// ---------------- legacy fp32 flash attention (fallback, small ws) ----------
__global__ __launch_bounds__(256)
void attn_k(const short* __restrict__ qbf, const float* __restrict__ pres,
            short* __restrict__ obf) {
  __shared__ float Ksf[32][64];
  __shared__ float Vsf[32][64];
  const int bh = blockIdx.x;
  const int q0 = ((int)gridDim.y - 1 - (int)blockIdx.y) * 64;
  const int t  = threadIdx.x;
  const int part = t & 3;
  const int row  = t >> 2;
  const int qr   = q0 + row;
  const int dbase = part * 16;
  const size_t qoff = ((size_t)bh * SS + qr) * KD + dbase;
  float q[16], o[16];
  #pragma unroll
  for (int i = 0; i < 16; ++i) q[i] = us2f((unsigned short)qbf[qoff + i]);
  #pragma unroll
  for (int i = 0; i < 16; ++i) o[i] = 0.f;
  float m = NEGSENT, l = 0.f;
  const float* Kb = pres + (size_t)bh * SS * KD;
  const float* Vb = pres + (size_t)PRES_HALF + (size_t)bh * SS * KD;
  const int nch = (q0 + 64) / 32;
  for (int ch = 0; ch < nch; ++ch) {
    const int kbase = ch * 32;
    __syncthreads();
    {
      const float4* ksrc = (const float4*)(Kb + (size_t)kbase * KD);
      const float4* vsrc = (const float4*)(Vb + (size_t)kbase * KD);
      float4* kdst = (float4*)&Ksf[0][0];
      float4* vdst = (float4*)&Vsf[0][0];
      #pragma unroll
      for (int i = 0; i < 2; ++i) {
        kdst[t + i * 256] = ksrc[t + i * 256];
        vdst[t + i * 256] = vsrc[t + i * 256];
      }
    }
    __syncthreads();
    float sc[32];
    #pragma unroll
    for (int kk = 0; kk < 32; ++kk) {
      float s = 0.f;
      #pragma unroll
      for (int i = 0; i < 16; ++i) s = fmaf(q[i], Ksf[kk][dbase + i], s);
      s += __shfl_xor(s, 1, 64);
      s += __shfl_xor(s, 2, 64);
      sc[kk] = (kbase + kk <= qr) ? s * 0.125f : NEGSENT;
    }
    float mc = sc[0];
    #pragma unroll
    for (int kk = 1; kk < 32; ++kk) mc = fmaxf(mc, sc[kk]);
    const float mn = fmaxf(m, mc);
    const float alpha = __expf(m - mn);
    l *= alpha;
    #pragma unroll
    for (int i = 0; i < 16; ++i) o[i] *= alpha;
    #pragma unroll
    for (int kk = 0; kk < 32; ++kk) {
      const float p = __expf(sc[kk] - mn);
      l += p;
      #pragma unroll
      for (int i = 0; i < 16; ++i) o[i] = fmaf(p, Vsf[kk][dbase + i], o[i]);
    }
    m = mn;
  }
  const float inv = 1.f / fmaxf(l, 1e-30f);
  const int bb = bh >> 4, h = bh & 15;
  const size_t ooff = ((size_t)(bb * SS + qr)) * DM + h * KD + dbase;
  #pragma unroll
  for (int i = 0; i < 16; ++i) obf[ooff + i] = f2s(o[i] * inv);
}

extern "C" void kernel_launch(void* const* d_in, const int* in_sizes, int n_in,
                              void* d_out, int out_size, void* d_ws, size_t ws_size,
                              hipStream_t stream) {
  const float* x      = (const float*)d_in[0];
  const float* w_attn = (const float*)d_in[2];
  const float* b_attn = (const float*)d_in[3];
  const float* w_proj = (const float*)d_in[4];
  const float* b_proj = (const float*)d_in[5];
  float* outf = (float*)d_out;   // fp32: [out0 4M | k 4M | v 4M] elements

  constexpr size_t MB = 1024 * 1024;
  if (ws_size >= 24 * MB) {
    // ---- MFMA-attention path ----
    // ws (shorts): [0,4M) x_bf then o_bf (lifetimes disjoint) |
    //              [4M,7M) w_attn_T | [7M,8M) w_proj_T | [8M,12M) q_bf
    // d_out out0 region (dead until proj): [0,4M) k_bf | [4M,8M) v_bfT
    short* ws0   = (short*)d_ws;
    short* x_bf  = ws0;
    short* o_bf  = ws0;
    short* wat_t = ws0 + (size_t)4 * 1024 * 1024;
    short* wpt_t = ws0 + (size_t)7 * 1024 * 1024;
    short* q_bf  = ws0 + (size_t)8 * 1024 * 1024;
    short* k_bf  = (short*)d_out;
    short* v_bft = k_bf + (size_t)PRES_HALF;

    cast_x_k<<<4096, 256, 0, stream>>>(x, x_bf);
    transpose_k<<<dim3(96, 32), 256, 0, stream>>>(w_attn, 3 * DM, wat_t);
    transpose_k<<<dim3(32, 32), 256, 0, stream>>>(w_proj, DM, wpt_t);

    qkv_mfma_k<<<dim3(24, 32), 256, 0, stream>>>(x_bf, wat_t, b_attn, q_bf, outf,
                                                 k_bf);

    v_tr_k<<<dim3(BB * NH, SS / 64), 256, 0, stream>>>(
        outf + OUT_ELEMS + PRES_HALF, v_bft);

    attn_mfma8_k<<<dim3(512), 256, 0, stream>>>(q_bf, k_bf, v_bft, o_bf);

    proj_mfma_k<<<dim3(8, 32), 256, 0, stream>>>(o_bf, wpt_t, b_proj, outf);
  } else {
    // ---- legacy fp32-attention fallback ----
    short* x_bf;
    short* q_bf;
    short* wat_t;
    short* wpt_t;
    short* o_bf;
    if (ws_size >= 16 * MB) {
      short* ws = (short*)d_ws;
      x_bf  = (short*)d_out;                 // out0 [0,8MB) dead until proj
      q_bf  = x_bf + OUT_ELEMS;              // out0 [8MB,16MB)
      wat_t = ws;
      wpt_t = wat_t + 3 * DM * DM;
      o_bf  = wat_t + 4 * DM * DM;
    } else {
      x_bf  = (short*)d_out;
      q_bf  = x_bf + OUT_ELEMS;
      wat_t = (short*)d_in[1];
      wpt_t = wat_t + 3 * DM * DM;
      o_bf  = wat_t + 4 * DM * DM;
    }
    cast_x_k<<<4096, 256, 0, stream>>>(x, x_bf);
    transpose_k<<<dim3(96, 32), 256, 0, stream>>>(w_attn, 3 * DM, wat_t);
    transpose_k<<<dim3(32, 32), 256, 0, stream>>>(w_proj, DM, wpt_t);
    qkv_mfma_k<<<dim3(24, 32), 256, 0, stream>>>(x_bf, wat_t, b_attn, q_bf, outf,
                                                 nullptr);
    attn_k<<<dim3(BB * NH, SS / 64), 256, 0, stream>>>(q_bf, outf + OUT_ELEMS, o_bf);
    proj_mfma_k<<<dim3(8, 32), 256, 0, stream>>>(o_bf, wpt_t, b_proj, outf);
  }
}

// Round 11
// 219.331 us; speedup vs baseline: 1.1942x; 1.0337x over previous
//
#include <hip/hip_runtime.h>
#include <math.h>

constexpr int BB = 2;
constexpr int SS = 2048;
constexpr int DM = 1024;
constexpr int NH = 16;
constexpr int KD = 64;
constexpr int OUT_ELEMS  = BB*SS*DM;     // 4194304 fp32 (output 0 region)
constexpr int PRES_HALF  = BB*NH*SS*KD;  // 4194304 fp32 (k or v)
#define NEGSENT (-1e30f)

typedef __attribute__((ext_vector_type(8))) short short8;   // 8 x bf16 bits
typedef __attribute__((ext_vector_type(4))) short short4v;  // 4 x bf16 bits
typedef __attribute__((ext_vector_type(4))) float f32x4;

__device__ __forceinline__ float us2f(unsigned short u) {
  union { unsigned int ui; float f; } c; c.ui = ((unsigned int)u) << 16; return c.f;
}
__device__ __forceinline__ short f2s(float f) {
  // round-to-nearest-even bf16 (finite inputs only) — software path
  union { float f; unsigned int u; } c; c.f = f;
  return (short)((c.u + 0x7FFFu + ((c.u >> 16) & 1u)) >> 16);
}
__device__ __forceinline__ short f2s_hw(float f) {
  // hardware RNE bf16 via v_cvt_pk_bf16_f32 (no builtin on gfx950 — T12).
  unsigned int r;
  asm("v_cvt_pk_bf16_f32 %0, %1, %1" : "=v"(r) : "v"(f));
  return (short)r;
}
__device__ __forceinline__ unsigned int pk2(float lo, float hi) {
  // [bf16(lo) | bf16(hi)<<16] in one instruction (S0->low, S1->high)
  unsigned int r;
  asm("v_cvt_pk_bf16_f32 %0, %1, %2" : "=v"(r) : "v"(lo), "v"(hi));
  return r;
}

#define GLOAD_LDS16(g, l) \
  __builtin_amdgcn_global_load_lds((const __attribute__((address_space(1))) void*)(g), \
                                   (__attribute__((address_space(3))) void*)(l), 16, 0, 0)

// ---------------- merged prep: cast x -> bf16 | transpose w_attn | w_proj ---
// blockIdx partition: [0,4096) cast, [4096,7168) w_attn T, [7168,8192) w_proj T.
// Saves 2 kernel-launch gaps vs 3 separate dispatches.
__global__ __launch_bounds__(256)
void prep_k(const float* __restrict__ x, short* __restrict__ xb,
            const float* __restrict__ wa, short* __restrict__ wat,
            const float* __restrict__ wp, short* __restrict__ wpt) {
  __shared__ float tl[32][33];
  const int bid = blockIdx.x;
  if (bid < 4096) {
    const size_t i = ((size_t)bid * 256 + threadIdx.x) * 4;
    const float4 v = *(const float4*)(x + i);
    short4v s; s.x = f2s(v.x); s.y = f2s(v.y); s.z = f2s(v.z); s.w = f2s(v.w);
    *(short4v*)(xb + i) = s;
    return;
  }
  const float* w; short* wt; int N, t;
  if (bid < 4096 + 3072) { w = wa; wt = wat; N = 3 * DM; t = bid - 4096;
    // grid was (96,32): n-blk = t%96, k-blk = t/96
  } else { w = wp; wt = wpt; N = DM; t = bid - 7168; }
  const int nb = (N == DM) ? 32 : 96;
  const int n0 = (t % nb) * 32, k0 = (t / nb) * 32;
  const int tx = threadIdx.x & 31, ty = threadIdx.x >> 5;   // 32 x 8
  #pragma unroll
  for (int i = 0; i < 4; ++i) {
    const int kk = ty + i * 8;
    tl[kk][tx] = w[(size_t)(k0 + kk) * N + n0 + tx];
  }
  __syncthreads();
  #pragma unroll
  for (int i = 0; i < 4; ++i) {
    const int nn = ty + i * 8;
    wt[(size_t)(n0 + nn) * 1024 + k0 + tx] = f2s(tl[tx][nn]);
  }
}

// ---------------- prep: transpose present-v fp32 [bh][s][64] -> bf16 [bh][64][s]
// Writes keys in PI-permuted order within each 64-key chunk:
//   PI(pos) = (pos&32) | ((pos&31)>>1) | ((pos&1)<<4)
// (pos 2j -> key j, 2j+1 -> key j+16, within each 32-half). PV in attn
// contracts P and V^T by POSITION, so permuting both is exact — this makes
// P pairs (k, k+16) adjacent so attn can pack them with one cvt_pk + b32 write.
__global__ __launch_bounds__(256)
void v_tr_k(const float* __restrict__ vf, short* __restrict__ vt) {
  __shared__ float tl[64][65];
  const int bh = blockIdx.x;                 // 0..31
  const int s0 = blockIdx.y * 64;            // 32 tiles (64-key chunks)
  const int tr = threadIdx.x >> 2;           // 0..63
  const int tc = (threadIdx.x & 3) * 16;
  const float* src = vf + ((size_t)bh * SS + s0) * KD;
  #pragma unroll
  for (int i = 0; i < 4; ++i) {
    const float4 v = *(const float4*)(src + (size_t)tr * KD + tc + i * 4);
    tl[tr][tc + i * 4 + 0] = v.x; tl[tr][tc + i * 4 + 1] = v.y;
    tl[tr][tc + i * 4 + 2] = v.z; tl[tr][tc + i * 4 + 3] = v.w;
  }
  __syncthreads();
  short8 o0, o1;
  #pragma unroll
  for (int i = 0; i < 8; ++i) {
    const int pos = tc + i;
    const int key = (pos & 32) | ((pos & 31) >> 1) | ((pos & 1) << 4);
    o0[i] = f2s(tl[key][tr]);
  }
  #pragma unroll
  for (int i = 0; i < 8; ++i) {
    const int pos = tc + 8 + i;
    const int key = (pos & 32) | ((pos & 31) >> 1) | ((pos & 1) << 4);
    o1[i] = f2s(tl[key][tr]);
  }
  short* dst = vt + ((size_t)bh * KD + tr) * SS + s0 + tc;
  *(short8*)(dst) = o0;
  *(short8*)(dst + 8) = o1;
}

// ---------------- MFMA GEMM core (m97 structure, BK=32 — proven best) -------
__device__ __forceinline__ void mfma_tile_loop(
    const short* __restrict__ A, const short* __restrict__ Bt,
    int m0, int n0, short* Asm, short* Bsm, f32x4 (*acc)[4]) {
  const int tid = threadIdx.x;
  const int lane = tid & 63;
  const int w = tid >> 6;
  const int wm = (w >> 1) * 64, wn = (w & 1) * 64;
  const int ln15 = lane & 15, quad = lane >> 4;
  for (int k0 = 0; k0 < 1024; k0 += 32) {
    #pragma unroll
    for (int j = 0; j < 2; ++j) {
      const int e = j * 256 + tid;          // 0..511
      const int r = e >> 2, cq = e & 3;     // row, 16B-chunk
      GLOAD_LDS16(A  + (size_t)(m0 + r) * 1024 + k0 + cq * 8, Asm + e * 8);
      GLOAD_LDS16(Bt + (size_t)(n0 + r) * 1024 + k0 + cq * 8, Bsm + e * 8);
    }
    __syncthreads();                        // drains vmcnt before barrier
    short8 af[4], bf[4];
    #pragma unroll
    for (int t = 0; t < 4; ++t)
      af[t] = *(const short8*)(Asm + (wm + t * 16 + ln15) * 32 + quad * 8);
    #pragma unroll
    for (int t = 0; t < 4; ++t)
      bf[t] = *(const short8*)(Bsm + (wn + t * 16 + ln15) * 32 + quad * 8);
    #pragma unroll
    for (int tm = 0; tm < 4; ++tm)
      #pragma unroll
      for (int tn = 0; tn < 4; ++tn)
        acc[tm][tn] = __builtin_amdgcn_mfma_f32_16x16x32_bf16(
            af[tm], bf[tn], acc[tm][tn], 0, 0, 0);
    __syncthreads();
  }
}

// ---------------- QKV GEMM: routes v,q,k = split(qkv) ----------------------
__global__ __launch_bounds__(256)
void qkv_mfma_k(const short* __restrict__ A, const short* __restrict__ Bt,
                const float* __restrict__ bias, short* __restrict__ qbf,
                float* __restrict__ outf, short* __restrict__ kbf) {
  __shared__ short Asm[128 * 32];
  __shared__ short Bsm[128 * 32];
  const int n0 = blockIdx.x * 128, m0 = blockIdx.y * 128;
  f32x4 acc[4][4] = {};
  mfma_tile_loop(A, Bt, m0, n0, Asm, Bsm, acc);
  const int lane = threadIdx.x & 63;
  const int w = threadIdx.x >> 6;
  const int wm = (w >> 1) * 64, wn = (w & 1) * 64;
  const int col = lane & 15, row4 = (lane >> 4) * 4;
  #pragma unroll
  for (int tm = 0; tm < 4; ++tm) {
    #pragma unroll
    for (int tn = 0; tn < 4; ++tn) {
      const int n = n0 + wn + tn * 16 + col;
      #pragma unroll
      for (int r = 0; r < 4; ++r) {
        const int m = m0 + wm + tm * 16 + row4 + r;
        const float val = acc[tm][tn][r] + bias[n];
        const int bb = m >> 11, s = m & 2047;
        const int c = n & 1023, h = c >> 6, d = c & 63;
        const size_t idx = ((size_t)(bb * NH + h) * SS + s) * KD + d;
        if (n < DM) {
          outf[(size_t)OUT_ELEMS + (size_t)PRES_HALF + idx] = val;   // v fp32
        } else if (n < 2 * DM) {
          qbf[idx] = f2s(val);                                        // q bf16
        } else {
          outf[(size_t)OUT_ELEMS + idx] = val;                        // k fp32
          if (kbf) kbf[idx] = f2s(val);
        }
      }
    }
  }
}

// ---------------- Output projection: o @ w_projT + b -> out0 fp32 -----------
__global__ __launch_bounds__(256)
void proj_mfma_k(const short* __restrict__ A, const short* __restrict__ Bt,
                 const float* __restrict__ bias, float* __restrict__ outf) {
  __shared__ short Asm[128 * 32];
  __shared__ short Bsm[128 * 32];
  const int n0 = blockIdx.x * 128, m0 = blockIdx.y * 128;
  f32x4 acc[4][4] = {};
  mfma_tile_loop(A, Bt, m0, n0, Asm, Bsm, acc);
  const int lane = threadIdx.x & 63;
  const int w = threadIdx.x >> 6;
  const int wm = (w >> 1) * 64, wn = (w & 1) * 64;
  const int col = lane & 15, row4 = (lane >> 4) * 4;
  #pragma unroll
  for (int tm = 0; tm < 4; ++tm) {
    #pragma unroll
    for (int tn = 0; tn < 4; ++tn) {
      const int n = n0 + wn + tn * 16 + col;
      const float b = bias[n];
      #pragma unroll
      for (int r = 0; r < 4; ++r) {
        const int m = m0 + wm + tm * 16 + row4 + r;
        outf[(size_t)m * DM + n] = acc[tm][tn][r] + b;
      }
    }
  }
}

// ---------------- staging: one 64-key chunk of K + V^T, 256 threads ---------
__device__ __forceinline__ void stage_kv4(const short* __restrict__ Kg,
                                          const short* __restrict__ Vg,
                                          int kb, short* Ksb, short* Vtb,
                                          int tid) {
  #pragma unroll
  for (int rd = 0; rd < 2; ++rd) {
    const int i = rd * 256 + tid;        // 0..511 : row = i>>3, grp = i&7
    const int row = i >> 3, grp = i & 7;
    const int sw = (grp ^ (row & 7)) << 3;
    GLOAD_LDS16(Kg + (size_t)(kb + row) * KD + sw, Ksb + i * 8);
    GLOAD_LDS16(Vg + (size_t)row * SS + kb + sw, Vtb + i * 8);
  }
}

// ---------------- MFMA causal flash attention (R10 structure + packed P) ----
// Uniform 2-pass pair blocks; HW cvt; cheap defer-max. New: P pairs packed
// with one v_cvt_pk_bf16_f32 + one ds_write_b32 (V^T is PI-permuted by
// v_tr_k so (k, k+16) sit adjacent by position): 16 cvt + 16 b16-stores
// -> 8 pk-cvt + 8 b32-stores per lane-chunk.
__global__ __launch_bounds__(256)
void attn_mfma9_k(const short* __restrict__ qbf, const short* __restrict__ kbf,
                  const short* __restrict__ vbft, short* __restrict__ obf) {
  __shared__ short Ks[2][64 * 64];    // K chunk  [key][d], swizzled
  __shared__ short Vt[2][64 * 64];    // V^T chunk [d][pos], swizzled (PI order)
  __shared__ short Ps[4][16 * 64];    // per-wave P [qrow][pos], swizzled
  const int bid = blockIdx.x;                     // 0..511
  const int xcd = bid & 7, g = bid >> 3;          // g 0..63
  const int rnd = g >> 4;                         // head-in-XCD 0..3
  const int p   = g & 15;                         // causal pair 0..15
  const int bh  = (xcd << 2) | rnd;
  const int tid = threadIdx.x;
  const int w   = tid >> 6;
  const int lane = tid & 63;
  const int ln15 = lane & 15, quad = lane >> 4;
  const int rswz = (ln15 & 7) << 3;               // fragment-read swizzle
  const float SC2 = 0.125f * 1.44269504f;         // scale * log2(e)
  const float THR = 8.0f;                         // defer-max threshold (raw)

  const short* Kg = kbf  + (size_t)bh * SS * KD;
  const short* Vg = vbft + (size_t)bh * KD * SS;
  short* Pw = Ps[w];
  const int bb = bh >> 4, h = bh & 15;

  #pragma unroll 1
  for (int pass = 0; pass < 2; ++pass) {
    const int qb = pass ? (31 - p) : p;
    const int q0 = qb * 64;
    const int nch = qb + 1;

    // Q fragments for this wave's 16 rows: row = ln15, k = kt*32 + quad*8
    short8 aq[2];
    {
      const short* qp = qbf + ((size_t)bh * SS + q0 + w * 16) * KD;
      aq[0] = *(const short8*)(qp + (size_t)ln15 * KD + quad * 8);
      aq[1] = *(const short8*)(qp + (size_t)ln15 * KD + 32 + quad * 8);
    }
    f32x4 O[4] = {};                    // [tn], rows quad*4+r
    float mreg[4], lreg[4];             // [r]
    #pragma unroll
    for (int r = 0; r < 4; ++r) { mreg[r] = NEGSENT; lreg[r] = 0.f; }

    stage_kv4(Kg, Vg, 0, Ks[0], Vt[0], tid);   // chunk 0 -> buf 0
    __syncthreads();

    for (int ch = 0; ch < nch; ++ch) {
      const int cur = ch & 1;
      if (ch + 1 < nch)                        // issue next-chunk loads first
        stage_kv4(Kg, Vg, (ch + 1) * 64, Ks[cur ^ 1], Vt[cur ^ 1], tid);
      const short* Kc = Ks[cur];
      const short* Vc = Vt[cur];

      // ---- QK^T: S[16 q][64 k] (actual key order) ----
      f32x4 S[4] = {};
      #pragma unroll
      for (int kt = 0; kt < 2; ++kt) {
        short8 bk[4];
        #pragma unroll
        for (int tn = 0; tn < 4; ++tn)
          bk[tn] = *(const short8*)(Kc + (tn * 16 + ln15) * 64 + ((kt * 32 + quad * 8) ^ rswz));
        #pragma unroll
        for (int tn = 0; tn < 4; ++tn)
          S[tn] = __builtin_amdgcn_mfma_f32_16x16x32_bf16(aq[kt], bk[tn], S[tn], 0, 0, 0);
      }

      // ---- causal mask on the diagonal chunk ----
      if (ch == qb) {
        const int rowl = w * 16 + quad * 4;
        #pragma unroll
        for (int tn = 0; tn < 4; ++tn) {
          const int colk = tn * 16 + ln15;
          #pragma unroll
          for (int r = 0; r < 4; ++r)
            if (colk > rowl + r) S[tn][r] = NEGSENT;
        }
      }

      // ---- cheap per-lane defer-max check (conservative, no shfl) ----
      {
        float lmax = S[0][0];
        #pragma unroll
        for (int tn = 0; tn < 4; ++tn)
          #pragma unroll
          for (int r = 0; r < 4; ++r) lmax = fmaxf(lmax, S[tn][r]);
        const float mmin = fminf(fminf(mreg[0], mreg[1]), fminf(mreg[2], mreg[3]));
        const bool ok = (lmax - mmin) <= THR;
        if (!__all((int)ok)) {                  // rare slow path: full rescale
          #pragma unroll
          for (int r = 0; r < 4; ++r) {
            float mx = fmaxf(fmaxf(fmaxf(S[0][r], S[1][r]), S[2][r]), S[3][r]);
            mx = fmaxf(mx, __shfl_xor(mx, 1, 64));
            mx = fmaxf(mx, __shfl_xor(mx, 2, 64));
            mx = fmaxf(mx, __shfl_xor(mx, 4, 64));
            mx = fmaxf(mx, __shfl_xor(mx, 8, 64));
            const float mn = fmaxf(mreg[r], mx);
            const float al = exp2f((mreg[r] - mn) * SC2);
            mreg[r] = mn;
            lreg[r] *= al;
            O[0][r] *= al; O[1][r] *= al; O[2][r] *= al; O[3][r] *= al;
          }
        }
      }

      // ---- P = exp2(fma(S,SC2,-m*SC2)); l += ...; packed P stores ----
      // Position layout (PI): (k=ln15, k=16+ln15) -> cols 2*ln15, 2*ln15+1;
      // (k=32+ln15, 48+ln15) -> cols 32+2*ln15, +1. One pk-cvt + b32 each.
      #pragma unroll
      for (int r = 0; r < 4; ++r) {
        const float mnsc = mreg[r] * SC2;
        const int prow = quad * 4 + r;
        const int rs = (prow & 7) << 3;
        float p0 = exp2f(fmaf(S[0][r], SC2, -mnsc));
        float p1 = exp2f(fmaf(S[1][r], SC2, -mnsc));
        float p2 = exp2f(fmaf(S[2][r], SC2, -mnsc));
        float p3 = exp2f(fmaf(S[3][r], SC2, -mnsc));
        lreg[r] += (p0 + p1) + (p2 + p3);
        *(unsigned int*)(Pw + prow * 64 + ((2 * ln15) ^ rs))      = pk2(p0, p1);
        *(unsigned int*)(Pw + prow * 64 + ((32 + 2 * ln15) ^ rs)) = pk2(p2, p3);
      }
      asm volatile("s_waitcnt lgkmcnt(0)" ::: "memory");  // own P writes landed
      __builtin_amdgcn_sched_barrier(0);                  // rule 18

      // ---- PV: O += P @ V (contraction by position; both PI-ordered) ----
      #pragma unroll
      for (int kt = 0; kt < 2; ++kt) {
        short8 ap = *(const short8*)(Pw + ln15 * 64 + ((kt * 32 + quad * 8) ^ rswz));
        short8 bv[4];
        #pragma unroll
        for (int tn = 0; tn < 4; ++tn)
          bv[tn] = *(const short8*)(Vc + (tn * 16 + ln15) * 64 + ((kt * 32 + quad * 8) ^ rswz));
        #pragma unroll
        for (int tn = 0; tn < 4; ++tn)
          O[tn] = __builtin_amdgcn_mfma_f32_16x16x32_bf16(ap, bv[tn], O[tn], 0, 0, 0);
      }
      __syncthreads();   // next buf staged+visible; prev reads done
    }

    // ---- finalize l and write o token-major (no LDS access) ----
    #pragma unroll
    for (int r = 0; r < 4; ++r) {
      float l = lreg[r];
      l += __shfl_xor(l, 1, 64);
      l += __shfl_xor(l, 2, 64);
      l += __shfl_xor(l, 4, 64);
      l += __shfl_xor(l, 8, 64);
      lreg[r] = 1.f / fmaxf(l, 1e-30f);
    }
    short* ob = obf + ((size_t)bb * SS + q0 + w * 16) * DM + h * KD;
    #pragma unroll
    for (int tn = 0; tn < 4; ++tn)
      #pragma unroll
      for (int r = 0; r < 4; ++r)
        ob[(size_t)(quad * 4 + r) * DM + tn * 16 + ln15] = f2s_hw(O[tn][r] * lreg[r]);
  }
}

// ---------------- legacy fp32 flash attention (fallback, small ws) ----------
__global__ __launch_bounds__(256)
void attn_k(const short* __restrict__ qbf, const float* __restrict__ pres,
            short* __restrict__ obf) {
  __shared__ float Ksf[32][64];
  __shared__ float Vsf[32][64];
  const int bh = blockIdx.x;
  const int q0 = ((int)gridDim.y - 1 - (int)blockIdx.y) * 64;
  const int t  = threadIdx.x;
  const int part = t & 3;
  const int row  = t >> 2;
  const int qr   = q0 + row;
  const int dbase = part * 16;
  const size_t qoff = ((size_t)bh * SS + qr) * KD + dbase;
  float q[16], o[16];
  #pragma unroll
  for (int i = 0; i < 16; ++i) q[i] = us2f((unsigned short)qbf[qoff + i]);
  #pragma unroll
  for (int i = 0; i < 16; ++i) o[i] = 0.f;
  float m = NEGSENT, l = 0.f;
  const float* Kb = pres + (size_t)bh * SS * KD;
  const float* Vb = pres + (size_t)PRES_HALF + (size_t)bh * SS * KD;
  const int nch = (q0 + 64) / 32;
  for (int ch = 0; ch < nch; ++ch) {
    const int kbase = ch * 32;
    __syncthreads();
    {
      const float4* ksrc = (const float4*)(Kb + (size_t)kbase * KD);
      const float4* vsrc = (const float4*)(Vb + (size_t)kbase * KD);
      float4* kdst = (float4*)&Ksf[0][0];
      float4* vdst = (float4*)&Vsf[0][0];
      #pragma unroll
      for (int i = 0; i < 2; ++i) {
        kdst[t + i * 256] = ksrc[t + i * 256];
        vdst[t + i * 256] = vsrc[t + i * 256];
      }
    }
    __syncthreads();
    float sc[32];
    #pragma unroll
    for (int kk = 0; kk < 32; ++kk) {
      float s = 0.f;
      #pragma unroll
      for (int i = 0; i < 16; ++i) s = fmaf(q[i], Ksf[kk][dbase + i], s);
      s += __shfl_xor(s, 1, 64);
      s += __shfl_xor(s, 2, 64);
      sc[kk] = (kbase + kk <= qr) ? s * 0.125f : NEGSENT;
    }
    float mc = sc[0];
    #pragma unroll
    for (int kk = 1; kk < 32; ++kk) mc = fmaxf(mc, sc[kk]);
    const float mn = fmaxf(m, mc);
    const float alpha = __expf(m - mn);
    l *= alpha;
    #pragma unroll
    for (int i = 0; i < 16; ++i) o[i] *= alpha;
    #pragma unroll
    for (int kk = 0; kk < 32; ++kk) {
      const float p = __expf(sc[kk] - mn);
      l += p;
      #pragma unroll
      for (int i = 0; i < 16; ++i) o[i] = fmaf(p, Vsf[kk][dbase + i], o[i]);
    }
    m = mn;
  }
  const float inv = 1.f / fmaxf(l, 1e-30f);
  const int bb = bh >> 4, h = bh & 15;
  const size_t ooff = ((size_t)(bb * SS + qr)) * DM + h * KD + dbase;
  #pragma unroll
  for (int i = 0; i < 16; ++i) obf[ooff + i] = f2s(o[i] * inv);
}

extern "C" void kernel_launch(void* const* d_in, const int* in_sizes, int n_in,
                              void* d_out, int out_size, void* d_ws, size_t ws_size,
                              hipStream_t stream) {
  const float* x      = (const float*)d_in[0];
  const float* w_attn = (const float*)d_in[2];
  const float* b_attn = (const float*)d_in[3];
  const float* w_proj = (const float*)d_in[4];
  const float* b_proj = (const float*)d_in[5];
  float* outf = (float*)d_out;   // fp32: [out0 4M | k 4M | v 4M] elements

  constexpr size_t MB = 1024 * 1024;
  if (ws_size >= 24 * MB) {
    // ---- MFMA-attention path ----
    short* ws0   = (short*)d_ws;
    short* x_bf  = ws0;
    short* o_bf  = ws0;
    short* wat_t = ws0 + (size_t)4 * 1024 * 1024;
    short* wpt_t = ws0 + (size_t)7 * 1024 * 1024;
    short* q_bf  = ws0 + (size_t)8 * 1024 * 1024;
    short* k_bf  = (short*)d_out;
    short* v_bft = k_bf + (size_t)PRES_HALF;

    prep_k<<<8192, 256, 0, stream>>>(x, x_bf, w_attn, wat_t, w_proj, wpt_t);

    qkv_mfma_k<<<dim3(24, 32), 256, 0, stream>>>(x_bf, wat_t, b_attn, q_bf, outf,
                                                 k_bf);

    v_tr_k<<<dim3(BB * NH, SS / 64), 256, 0, stream>>>(
        outf + OUT_ELEMS + PRES_HALF, v_bft);

    attn_mfma9_k<<<dim3(512), 256, 0, stream>>>(q_bf, k_bf, v_bft, o_bf);

    proj_mfma_k<<<dim3(8, 32), 256, 0, stream>>>(o_bf, wpt_t, b_proj, outf);
  } else {
    // ---- legacy fp32-attention fallback ----
    short* x_bf;
    short* q_bf;
    short* wat_t;
    short* wpt_t;
    short* o_bf;
    if (ws_size >= 16 * MB) {
      short* ws = (short*)d_ws;
      x_bf  = (short*)d_out;                 // out0 [0,8MB) dead until proj
      q_bf  = x_bf + OUT_ELEMS;              // out0 [8MB,16MB)
      wat_t = ws;
      wpt_t = wat_t + 3 * DM * DM;
      o_bf  = wat_t + 4 * DM * DM;
    } else {
      x_bf  = (short*)d_out;
      q_bf  = x_bf + OUT_ELEMS;
      wat_t = (short*)d_in[1];
      wpt_t = wat_t + 3 * DM * DM;
      o_bf  = wat_t + 4 * DM * DM;
    }
    prep_k<<<8192, 256, 0, stream>>>(x, x_bf, w_attn, wat_t, w_proj, wpt_t);
    qkv_mfma_k<<<dim3(24, 32), 256, 0, stream>>>(x_bf, wat_t, b_attn, q_bf, outf,
                                                 nullptr);
    attn_k<<<dim3(BB * NH, SS / 64), 256, 0, stream>>>(q_bf, outf + OUT_ELEMS, o_bf);
    proj_mfma_k<<<dim3(8, 32), 256, 0, stream>>>(o_bf, wpt_t, b_proj, outf);
  }
}

// Round 12
// 219.312 us; speedup vs baseline: 1.1943x; 1.0001x over previous
//
#include <hip/hip_runtime.h>
#include <math.h>

constexpr int BB = 2;
constexpr int SS = 2048;
constexpr int DM = 1024;
constexpr int NH = 16;
constexpr int KD = 64;
constexpr int OUT_ELEMS  = BB*SS*DM;     // 4194304 fp32 (output 0 region)
constexpr int PRES_HALF  = BB*NH*SS*KD;  // 4194304 fp32 (k or v)
#define NEGSENT (-1e30f)

typedef __attribute__((ext_vector_type(8))) short short8;   // 8 x bf16 bits
typedef __attribute__((ext_vector_type(4))) short short4v;  // 4 x bf16 bits
typedef __attribute__((ext_vector_type(4))) float f32x4;

__device__ __forceinline__ float us2f(unsigned short u) {
  union { unsigned int ui; float f; } c; c.ui = ((unsigned int)u) << 16; return c.f;
}
__device__ __forceinline__ short f2s(float f) {
  // round-to-nearest-even bf16 (finite inputs only) — software path
  union { float f; unsigned int u; } c; c.f = f;
  return (short)((c.u + 0x7FFFu + ((c.u >> 16) & 1u)) >> 16);
}
__device__ __forceinline__ short f2s_hw(float f) {
  // hardware RNE bf16 via v_cvt_pk_bf16_f32 (no builtin on gfx950 — T12).
  unsigned int r;
  asm("v_cvt_pk_bf16_f32 %0, %1, %1" : "=v"(r) : "v"(f));
  return (short)r;
}
__device__ __forceinline__ unsigned int pk2(float lo, float hi) {
  // [bf16(lo) | bf16(hi)<<16] in one instruction (S0->low, S1->high)
  unsigned int r;
  asm("v_cvt_pk_bf16_f32 %0, %1, %2" : "=v"(r) : "v"(lo), "v"(hi));
  return r;
}

#define GLOAD_LDS16(g, l) \
  __builtin_amdgcn_global_load_lds((const __attribute__((address_space(1))) void*)(g), \
                                   (__attribute__((address_space(3))) void*)(l), 16, 0, 0)

// ---------------- merged prep: cast x -> bf16 | transpose w_attn | w_proj ---
// blockIdx partition: [0,4096) cast, [4096,7168) w_attn T, [7168,8192) w_proj T.
__global__ __launch_bounds__(256)
void prep_k(const float* __restrict__ x, short* __restrict__ xb,
            const float* __restrict__ wa, short* __restrict__ wat,
            const float* __restrict__ wp, short* __restrict__ wpt) {
  __shared__ float tl[32][33];
  const int bid = blockIdx.x;
  if (bid < 4096) {
    const size_t i = ((size_t)bid * 256 + threadIdx.x) * 4;
    const float4 v = *(const float4*)(x + i);
    uint2 o; o.x = pk2(v.x, v.y); o.y = pk2(v.z, v.w);   // 2 instr vs ~14
    *(uint2*)(xb + i) = o;
    return;
  }
  const float* w; short* wt; int N, t;
  if (bid < 4096 + 3072) { w = wa; wt = wat; N = 3 * DM; t = bid - 4096; }
  else { w = wp; wt = wpt; N = DM; t = bid - 7168; }
  const int nb = (N == DM) ? 32 : 96;
  const int n0 = (t % nb) * 32, k0 = (t / nb) * 32;
  const int tx = threadIdx.x & 31, ty = threadIdx.x >> 5;   // 32 x 8
  #pragma unroll
  for (int i = 0; i < 4; ++i) {
    const int kk = ty + i * 8;
    tl[kk][tx] = w[(size_t)(k0 + kk) * N + n0 + tx];
  }
  __syncthreads();
  #pragma unroll
  for (int i = 0; i < 4; ++i) {
    const int nn = ty + i * 8;
    wt[(size_t)(n0 + nn) * 1024 + k0 + tx] = f2s(tl[tx][nn]);
  }
}

// ---------------- prep: transpose present-v fp32 [bh][s][64] -> bf16 [bh][64][s]
// Keys written in PI-permuted order within each 64-key chunk:
//   PI(pos) = (pos&32) | ((pos&31)>>1) | ((pos&1)<<4)
// PV in attn contracts by POSITION, so permuting both P and V^T is exact.
__global__ __launch_bounds__(256)
void v_tr_k(const float* __restrict__ vf, short* __restrict__ vt) {
  __shared__ float tl[64][65];
  const int bh = blockIdx.x;                 // 0..31
  const int s0 = blockIdx.y * 64;            // 32 tiles (64-key chunks)
  const int tr = threadIdx.x >> 2;           // 0..63
  const int tc = (threadIdx.x & 3) * 16;
  const float* src = vf + ((size_t)bh * SS + s0) * KD;
  #pragma unroll
  for (int i = 0; i < 4; ++i) {
    const float4 v = *(const float4*)(src + (size_t)tr * KD + tc + i * 4);
    tl[tr][tc + i * 4 + 0] = v.x; tl[tr][tc + i * 4 + 1] = v.y;
    tl[tr][tc + i * 4 + 2] = v.z; tl[tr][tc + i * 4 + 3] = v.w;
  }
  __syncthreads();
  uint4 o0, o1;
  unsigned int* p0 = (unsigned int*)&o0;
  unsigned int* p1 = (unsigned int*)&o1;
  #pragma unroll
  for (int j = 0; j < 4; ++j) {
    int pos = tc + 2 * j;
    int k0 = (pos & 32) | ((pos & 31) >> 1) | ((pos & 1) << 4);
    int k1 = ((pos + 1) & 32) | (((pos + 1) & 31) >> 1) | (((pos + 1) & 1) << 4);
    p0[j] = pk2(tl[k0][tr], tl[k1][tr]);
  }
  #pragma unroll
  for (int j = 0; j < 4; ++j) {
    int pos = tc + 8 + 2 * j;
    int k0 = (pos & 32) | ((pos & 31) >> 1) | ((pos & 1) << 4);
    int k1 = ((pos + 1) & 32) | (((pos + 1) & 31) >> 1) | (((pos + 1) & 1) << 4);
    p1[j] = pk2(tl[k0][tr], tl[k1][tr]);
  }
  short* dst = vt + ((size_t)bh * KD + tr) * SS + s0 + tc;
  *(uint4*)(dst) = o0;          // 32B-aligned (tc multiple of 16 shorts)
  *(uint4*)(dst + 8) = o1;
}

// ---------------- MFMA GEMM core (m97 structure, BK=32 — proven best) -------
__device__ __forceinline__ void mfma_tile_loop(
    const short* __restrict__ A, const short* __restrict__ Bt,
    int m0, int n0, short* Asm, short* Bsm, f32x4 (*acc)[4]) {
  const int tid = threadIdx.x;
  const int lane = tid & 63;
  const int w = tid >> 6;
  const int wm = (w >> 1) * 64, wn = (w & 1) * 64;
  const int ln15 = lane & 15, quad = lane >> 4;
  for (int k0 = 0; k0 < 1024; k0 += 32) {
    #pragma unroll
    for (int j = 0; j < 2; ++j) {
      const int e = j * 256 + tid;          // 0..511
      const int r = e >> 2, cq = e & 3;     // row, 16B-chunk
      GLOAD_LDS16(A  + (size_t)(m0 + r) * 1024 + k0 + cq * 8, Asm + e * 8);
      GLOAD_LDS16(Bt + (size_t)(n0 + r) * 1024 + k0 + cq * 8, Bsm + e * 8);
    }
    __syncthreads();                        // drains vmcnt before barrier
    short8 af[4], bf[4];
    #pragma unroll
    for (int t = 0; t < 4; ++t)
      af[t] = *(const short8*)(Asm + (wm + t * 16 + ln15) * 32 + quad * 8);
    #pragma unroll
    for (int t = 0; t < 4; ++t)
      bf[t] = *(const short8*)(Bsm + (wn + t * 16 + ln15) * 32 + quad * 8);
    #pragma unroll
    for (int tm = 0; tm < 4; ++tm)
      #pragma unroll
      for (int tn = 0; tn < 4; ++tn)
        acc[tm][tn] = __builtin_amdgcn_mfma_f32_16x16x32_bf16(
            af[tm], bf[tn], acc[tm][tn], 0, 0, 0);
    __syncthreads();
  }
}

// ---------------- QKV GEMM: routes v,q,k = split(qkv) ----------------------
// Epilogue strength-reduced: bb block-uniform (128-row tiles never straddle
// the 2048 boundary), h/d/branch per-tn uniform, idx affine in (tm,r).
__global__ __launch_bounds__(256)
void qkv_mfma_k(const short* __restrict__ A, const short* __restrict__ Bt,
                const float* __restrict__ bias, short* __restrict__ qbf,
                float* __restrict__ outf, short* __restrict__ kbf) {
  __shared__ short Asm[128 * 32];
  __shared__ short Bsm[128 * 32];
  const int n0 = blockIdx.x * 128, m0 = blockIdx.y * 128;
  f32x4 acc[4][4] = {};
  mfma_tile_loop(A, Bt, m0, n0, Asm, Bsm, acc);
  const int lane = threadIdx.x & 63;
  const int w = threadIdx.x >> 6;
  const int wm = (w >> 1) * 64, wn = (w & 1) * 64;
  const int col = lane & 15, row4 = (lane >> 4) * 4;
  const int mbase = m0 + wm;
  const int bb = mbase >> 11;                    // block-uniform
  const int sbase = (mbase & 2047) + row4;
  #pragma unroll
  for (int tn = 0; tn < 4; ++tn) {
    const int n = n0 + wn + tn * 16 + col;
    const float bv = bias[n];
    const int c = n & 1023, h = c >> 6, d = c & 63;
    const size_t base = ((size_t)(bb * NH + h) * SS) * KD + d;
    #pragma unroll
    for (int tm = 0; tm < 4; ++tm) {
      const size_t sb = base + (size_t)(sbase + tm * 16) * KD;
      #pragma unroll
      for (int r = 0; r < 4; ++r) {
        const float val = acc[tm][tn][r] + bv;
        const size_t idx = sb + (size_t)r * KD;
        if (n < DM) {
          outf[(size_t)OUT_ELEMS + (size_t)PRES_HALF + idx] = val;   // v fp32
        } else if (n < 2 * DM) {
          qbf[idx] = f2s_hw(val);                                     // q bf16
        } else {
          outf[(size_t)OUT_ELEMS + idx] = val;                        // k fp32
          if (kbf) kbf[idx] = f2s_hw(val);
        }
      }
    }
  }
}

// ---------------- Output projection: o @ w_projT + b -> out0 fp32 -----------
// R12: 128x64 tiles, grid (16,32) = 512 blocks = 2/CU (was 256 = 1/CU,
// 1 wave/SIMD with every barrier latency-exposed). 4 waves as 2x2 over
// (128,64); per-wave 64x32 = acc[4][2]. LDS 12 KB.
__global__ __launch_bounds__(256)
void proj_mfma_k(const short* __restrict__ A, const short* __restrict__ Bt,
                 const float* __restrict__ bias, float* __restrict__ outf) {
  __shared__ short Asm[128 * 32];
  __shared__ short Bsm[64 * 32];
  const int n0 = blockIdx.x * 64, m0 = blockIdx.y * 128;
  const int tid = threadIdx.x;
  const int lane = tid & 63;
  const int w = tid >> 6;
  const int wm = (w >> 1) * 64, wn = (w & 1) * 32;
  const int ln15 = lane & 15, quad = lane >> 4;
  f32x4 acc[4][2] = {};
  for (int k0 = 0; k0 < 1024; k0 += 32) {
    #pragma unroll
    for (int j = 0; j < 2; ++j) {
      const int e = j * 256 + tid;          // 0..511
      const int r = e >> 2, cq = e & 3;     // row 0..127
      GLOAD_LDS16(A + (size_t)(m0 + r) * 1024 + k0 + cq * 8, Asm + e * 8);
    }
    {
      const int r = tid >> 2, cq = tid & 3; // row 0..63
      GLOAD_LDS16(Bt + (size_t)(n0 + r) * 1024 + k0 + cq * 8, Bsm + tid * 8);
    }
    __syncthreads();
    short8 af[4], bf[2];
    #pragma unroll
    for (int t = 0; t < 4; ++t)
      af[t] = *(const short8*)(Asm + (wm + t * 16 + ln15) * 32 + quad * 8);
    #pragma unroll
    for (int t = 0; t < 2; ++t)
      bf[t] = *(const short8*)(Bsm + (wn + t * 16 + ln15) * 32 + quad * 8);
    #pragma unroll
    for (int tm = 0; tm < 4; ++tm)
      #pragma unroll
      for (int tn = 0; tn < 2; ++tn)
        acc[tm][tn] = __builtin_amdgcn_mfma_f32_16x16x32_bf16(
            af[tm], bf[tn], acc[tm][tn], 0, 0, 0);
    __syncthreads();
  }
  const int col = ln15, row4 = quad * 4;
  #pragma unroll
  for (int tm = 0; tm < 4; ++tm) {
    #pragma unroll
    for (int tn = 0; tn < 2; ++tn) {
      const int n = n0 + wn + tn * 16 + col;
      const float b = bias[n];
      #pragma unroll
      for (int r = 0; r < 4; ++r) {
        const int m = m0 + wm + tm * 16 + row4 + r;
        outf[(size_t)m * DM + n] = acc[tm][tn][r] + b;
      }
    }
  }
}

// ---------------- staging: one 64-key chunk of K + V^T, 256 threads ---------
__device__ __forceinline__ void stage_kv4(const short* __restrict__ Kg,
                                          const short* __restrict__ Vg,
                                          int kb, short* Ksb, short* Vtb,
                                          int tid) {
  #pragma unroll
  for (int rd = 0; rd < 2; ++rd) {
    const int i = rd * 256 + tid;        // 0..511 : row = i>>3, grp = i&7
    const int row = i >> 3, grp = i & 7;
    const int sw = (grp ^ (row & 7)) << 3;
    GLOAD_LDS16(Kg + (size_t)(kb + row) * KD + sw, Ksb + i * 8);
    GLOAD_LDS16(Vg + (size_t)row * SS + kb + sw, Vtb + i * 8);
  }
}

// ---------------- MFMA causal flash attention (R11 — frozen best) -----------
__global__ __launch_bounds__(256)
void attn_mfma9_k(const short* __restrict__ qbf, const short* __restrict__ kbf,
                  const short* __restrict__ vbft, short* __restrict__ obf) {
  __shared__ short Ks[2][64 * 64];    // K chunk  [key][d], swizzled
  __shared__ short Vt[2][64 * 64];    // V^T chunk [d][pos], swizzled (PI order)
  __shared__ short Ps[4][16 * 64];    // per-wave P [qrow][pos], swizzled
  const int bid = blockIdx.x;                     // 0..511
  const int xcd = bid & 7, g = bid >> 3;          // g 0..63
  const int rnd = g >> 4;                         // head-in-XCD 0..3
  const int p   = g & 15;                         // causal pair 0..15
  const int bh  = (xcd << 2) | rnd;
  const int tid = threadIdx.x;
  const int w   = tid >> 6;
  const int lane = tid & 63;
  const int ln15 = lane & 15, quad = lane >> 4;
  const int rswz = (ln15 & 7) << 3;               // fragment-read swizzle
  const float SC2 = 0.125f * 1.44269504f;         // scale * log2(e)
  const float THR = 8.0f;                         // defer-max threshold (raw)

  const short* Kg = kbf  + (size_t)bh * SS * KD;
  const short* Vg = vbft + (size_t)bh * KD * SS;
  short* Pw = Ps[w];
  const int bb = bh >> 4, h = bh & 15;

  #pragma unroll 1
  for (int pass = 0; pass < 2; ++pass) {
    const int qb = pass ? (31 - p) : p;
    const int q0 = qb * 64;
    const int nch = qb + 1;

    short8 aq[2];
    {
      const short* qp = qbf + ((size_t)bh * SS + q0 + w * 16) * KD;
      aq[0] = *(const short8*)(qp + (size_t)ln15 * KD + quad * 8);
      aq[1] = *(const short8*)(qp + (size_t)ln15 * KD + 32 + quad * 8);
    }
    f32x4 O[4] = {};                    // [tn], rows quad*4+r
    float mreg[4], lreg[4];             // [r]
    #pragma unroll
    for (int r = 0; r < 4; ++r) { mreg[r] = NEGSENT; lreg[r] = 0.f; }

    stage_kv4(Kg, Vg, 0, Ks[0], Vt[0], tid);   // chunk 0 -> buf 0
    __syncthreads();

    for (int ch = 0; ch < nch; ++ch) {
      const int cur = ch & 1;
      if (ch + 1 < nch)                        // issue next-chunk loads first
        stage_kv4(Kg, Vg, (ch + 1) * 64, Ks[cur ^ 1], Vt[cur ^ 1], tid);
      const short* Kc = Ks[cur];
      const short* Vc = Vt[cur];

      // ---- QK^T: S[16 q][64 k] (actual key order) ----
      f32x4 S[4] = {};
      #pragma unroll
      for (int kt = 0; kt < 2; ++kt) {
        short8 bk[4];
        #pragma unroll
        for (int tn = 0; tn < 4; ++tn)
          bk[tn] = *(const short8*)(Kc + (tn * 16 + ln15) * 64 + ((kt * 32 + quad * 8) ^ rswz));
        #pragma unroll
        for (int tn = 0; tn < 4; ++tn)
          S[tn] = __builtin_amdgcn_mfma_f32_16x16x32_bf16(aq[kt], bk[tn], S[tn], 0, 0, 0);
      }

      // ---- causal mask on the diagonal chunk ----
      if (ch == qb) {
        const int rowl = w * 16 + quad * 4;
        #pragma unroll
        for (int tn = 0; tn < 4; ++tn) {
          const int colk = tn * 16 + ln15;
          #pragma unroll
          for (int r = 0; r < 4; ++r)
            if (colk > rowl + r) S[tn][r] = NEGSENT;
        }
      }

      // ---- cheap per-lane defer-max check (conservative, no shfl) ----
      {
        float lmax = S[0][0];
        #pragma unroll
        for (int tn = 0; tn < 4; ++tn)
          #pragma unroll
          for (int r = 0; r < 4; ++r) lmax = fmaxf(lmax, S[tn][r]);
        const float mmin = fminf(fminf(mreg[0], mreg[1]), fminf(mreg[2], mreg[3]));
        const bool ok = (lmax - mmin) <= THR;
        if (!__all((int)ok)) {                  // rare slow path: full rescale
          #pragma unroll
          for (int r = 0; r < 4; ++r) {
            float mx = fmaxf(fmaxf(fmaxf(S[0][r], S[1][r]), S[2][r]), S[3][r]);
            mx = fmaxf(mx, __shfl_xor(mx, 1, 64));
            mx = fmaxf(mx, __shfl_xor(mx, 2, 64));
            mx = fmaxf(mx, __shfl_xor(mx, 4, 64));
            mx = fmaxf(mx, __shfl_xor(mx, 8, 64));
            const float mn = fmaxf(mreg[r], mx);
            const float al = exp2f((mreg[r] - mn) * SC2);
            mreg[r] = mn;
            lreg[r] *= al;
            O[0][r] *= al; O[1][r] *= al; O[2][r] *= al; O[3][r] *= al;
          }
        }
      }

      // ---- P = exp2(fma(S,SC2,-m*SC2)); l += ...; packed P stores ----
      #pragma unroll
      for (int r = 0; r < 4; ++r) {
        const float mnsc = mreg[r] * SC2;
        const int prow = quad * 4 + r;
        const int rs = (prow & 7) << 3;
        float p0 = exp2f(fmaf(S[0][r], SC2, -mnsc));
        float p1 = exp2f(fmaf(S[1][r], SC2, -mnsc));
        float p2 = exp2f(fmaf(S[2][r], SC2, -mnsc));
        float p3 = exp2f(fmaf(S[3][r], SC2, -mnsc));
        lreg[r] += (p0 + p1) + (p2 + p3);
        *(unsigned int*)(Pw + prow * 64 + ((2 * ln15) ^ rs))      = pk2(p0, p1);
        *(unsigned int*)(Pw + prow * 64 + ((32 + 2 * ln15) ^ rs)) = pk2(p2, p3);
      }
      asm volatile("s_waitcnt lgkmcnt(0)" ::: "memory");  // own P writes landed
      __builtin_amdgcn_sched_barrier(0);                  // rule 18

      // ---- PV: O += P @ V (contraction by position; both PI-ordered) ----
      #pragma unroll
      for (int kt = 0; kt < 2; ++kt) {
        short8 ap = *(const short8*)(Pw + ln15 * 64 + ((kt * 32 + quad * 8) ^ rswz));
        short8 bv[4];
        #pragma unroll
        for (int tn = 0; tn < 4; ++tn)
          bv[tn] = *(const short8*)(Vc + (tn * 16 + ln15) * 64 + ((kt * 32 + quad * 8) ^ rswz));
        #pragma unroll
        for (int tn = 0; tn < 4; ++tn)
          O[tn] = __builtin_amdgcn_mfma_f32_16x16x32_bf16(ap, bv[tn], O[tn], 0, 0, 0);
      }
      __syncthreads();   // next buf staged+visible; prev reads done
    }

    // ---- finalize l and write o token-major (no LDS access) ----
    #pragma unroll
    for (int r = 0; r < 4; ++r) {
      float l = lreg[r];
      l += __shfl_xor(l, 1, 64);
      l += __shfl_xor(l, 2, 64);
      l += __shfl_xor(l, 4, 64);
      l += __shfl_xor(l, 8, 64);
      lreg[r] = 1.f / fmaxf(l, 1e-30f);
    }
    short* ob = obf + ((size_t)bb * SS + q0 + w * 16) * DM + h * KD;
    #pragma unroll
    for (int tn = 0; tn < 4; ++tn)
      #pragma unroll
      for (int r = 0; r < 4; ++r)
        ob[(size_t)(quad * 4 + r) * DM + tn * 16 + ln15] = f2s_hw(O[tn][r] * lreg[r]);
  }
}

// ---------------- legacy fp32 flash attention (fallback, small ws) ----------
__global__ __launch_bounds__(256)
void attn_k(const short* __restrict__ qbf, const float* __restrict__ pres,
            short* __restrict__ obf) {
  __shared__ float Ksf[32][64];
  __shared__ float Vsf[32][64];
  const int bh = blockIdx.x;
  const int q0 = ((int)gridDim.y - 1 - (int)blockIdx.y) * 64;
  const int t  = threadIdx.x;
  const int part = t & 3;
  const int row  = t >> 2;
  const int qr   = q0 + row;
  const int dbase = part * 16;
  const size_t qoff = ((size_t)bh * SS + qr) * KD + dbase;
  float q[16], o[16];
  #pragma unroll
  for (int i = 0; i < 16; ++i) q[i] = us2f((unsigned short)qbf[qoff + i]);
  #pragma unroll
  for (int i = 0; i < 16; ++i) o[i] = 0.f;
  float m = NEGSENT, l = 0.f;
  const float* Kb = pres + (size_t)bh * SS * KD;
  const float* Vb = pres + (size_t)PRES_HALF + (size_t)bh * SS * KD;
  const int nch = (q0 + 64) / 32;
  for (int ch = 0; ch < nch; ++ch) {
    const int kbase = ch * 32;
    __syncthreads();
    {
      const float4* ksrc = (const float4*)(Kb + (size_t)kbase * KD);
      const float4* vsrc = (const float4*)(Vb + (size_t)kbase * KD);
      float4* kdst = (float4*)&Ksf[0][0];
      float4* vdst = (float4*)&Vsf[0][0];
      #pragma unroll
      for (int i = 0; i < 2; ++i) {
        kdst[t + i * 256] = ksrc[t + i * 256];
        vdst[t + i * 256] = vsrc[t + i * 256];
      }
    }
    __syncthreads();
    float sc[32];
    #pragma unroll
    for (int kk = 0; kk < 32; ++kk) {
      float s = 0.f;
      #pragma unroll
      for (int i = 0; i < 16; ++i) s = fmaf(q[i], Ksf[kk][dbase + i], s);
      s += __shfl_xor(s, 1, 64);
      s += __shfl_xor(s, 2, 64);
      sc[kk] = (kbase + kk <= qr) ? s * 0.125f : NEGSENT;
    }
    float mc = sc[0];
    #pragma unroll
    for (int kk = 1; kk < 32; ++kk) mc = fmaxf(mc, sc[kk]);
    const float mn = fmaxf(m, mc);
    const float alpha = __expf(m - mn);
    l *= alpha;
    #pragma unroll
    for (int i = 0; i < 16; ++i) o[i] *= alpha;
    #pragma unroll
    for (int kk = 0; kk < 32; ++kk) {
      const float p = __expf(sc[kk] - mn);
      l += p;
      #pragma unroll
      for (int i = 0; i < 16; ++i) o[i] = fmaf(p, Vsf[kk][dbase + i], o[i]);
    }
    m = mn;
  }
  const float inv = 1.f / fmaxf(l, 1e-30f);
  const int bb = bh >> 4, h = bh & 15;
  const size_t ooff = ((size_t)(bb * SS + qr)) * DM + h * KD + dbase;
  #pragma unroll
  for (int i = 0; i < 16; ++i) obf[ooff + i] = f2s(o[i] * inv);
}

extern "C" void kernel_launch(void* const* d_in, const int* in_sizes, int n_in,
                              void* d_out, int out_size, void* d_ws, size_t ws_size,
                              hipStream_t stream) {
  const float* x      = (const float*)d_in[0];
  const float* w_attn = (const float*)d_in[2];
  const float* b_attn = (const float*)d_in[3];
  const float* w_proj = (const float*)d_in[4];
  const float* b_proj = (const float*)d_in[5];
  float* outf = (float*)d_out;   // fp32: [out0 4M | k 4M | v 4M] elements

  constexpr size_t MB = 1024 * 1024;
  if (ws_size >= 24 * MB) {
    // ---- MFMA-attention path ----
    short* ws0   = (short*)d_ws;
    short* x_bf  = ws0;
    short* o_bf  = ws0;
    short* wat_t = ws0 + (size_t)4 * 1024 * 1024;
    short* wpt_t = ws0 + (size_t)7 * 1024 * 1024;
    short* q_bf  = ws0 + (size_t)8 * 1024 * 1024;
    short* k_bf  = (short*)d_out;
    short* v_bft = k_bf + (size_t)PRES_HALF;

    prep_k<<<8192, 256, 0, stream>>>(x, x_bf, w_attn, wat_t, w_proj, wpt_t);

    qkv_mfma_k<<<dim3(24, 32), 256, 0, stream>>>(x_bf, wat_t, b_attn, q_bf, outf,
                                                 k_bf);

    v_tr_k<<<dim3(BB * NH, SS / 64), 256, 0, stream>>>(
        outf + OUT_ELEMS + PRES_HALF, v_bft);

    attn_mfma9_k<<<dim3(512), 256, 0, stream>>>(q_bf, k_bf, v_bft, o_bf);

    proj_mfma_k<<<dim3(16, 32), 256, 0, stream>>>(o_bf, wpt_t, b_proj, outf);
  } else {
    // ---- legacy fp32-attention fallback ----
    short* x_bf;
    short* q_bf;
    short* wat_t;
    short* wpt_t;
    short* o_bf;
    if (ws_size >= 16 * MB) {
      short* ws = (short*)d_ws;
      x_bf  = (short*)d_out;                 // out0 [0,8MB) dead until proj
      q_bf  = x_bf + OUT_ELEMS;              // out0 [8MB,16MB)
      wat_t = ws;
      wpt_t = wat_t + 3 * DM * DM;
      o_bf  = wat_t + 4 * DM * DM;
    } else {
      x_bf  = (short*)d_out;
      q_bf  = x_bf + OUT_ELEMS;
      wat_t = (short*)d_in[1];
      wpt_t = wat_t + 3 * DM * DM;
      o_bf  = wat_t + 4 * DM * DM;
    }
    prep_k<<<8192, 256, 0, stream>>>(x, x_bf, w_attn, wat_t, w_proj, wpt_t);
    qkv_mfma_k<<<dim3(24, 32), 256, 0, stream>>>(x_bf, wat_t, b_attn, q_bf, outf,
                                                 nullptr);
    attn_k<<<dim3(BB * NH, SS / 64), 256, 0, stream>>>(q_bf, outf + OUT_ELEMS, o_bf);
    proj_mfma_k<<<dim3(16, 32), 256, 0, stream>>>(o_bf, wpt_t, b_proj, outf);
  }
}